// Round 8
// baseline (1363.797 us; speedup 1.0000x reference)
//
#include <hip/hip_runtime.h>
#include <cstdint>
#include <cstddef>

#define T_TOK 4096
#define H_DIM 1024
#define I_DIM 2816
#define E_NUM 9
#define MAXTILE 76

typedef __bf16 bf16;
typedef bf16 bf16x8 __attribute__((ext_vector_type(8)));
typedef float f32x4 __attribute__((ext_vector_type(4)));

constexpr int BM = 128, BN = 128, BK = 32;

// async global->LDS, 16B per lane; LDS dest must be linear (wave-uniform base + lane*16)
#define GL16(gp, lp)                                                                   \
  __builtin_amdgcn_global_load_lds((const __attribute__((address_space(1))) void*)(gp), \
                                   (__attribute__((address_space(3))) void*)(lp), 16, 0, 0)

// ---------------- x: fp32 -> bf16 ----------------
__global__ __launch_bounds__(256) void k_xcast(const float* __restrict__ x, bf16* __restrict__ xb) {
  size_t i = ((size_t)blockIdx.x * 256 + threadIdx.x) * 8;
  float4 a = *reinterpret_cast<const float4*>(x + i);
  float4 b = *reinterpret_cast<const float4*>(x + i + 4);
  bf16x8 v;
  v[0]=(bf16)a.x; v[1]=(bf16)a.y; v[2]=(bf16)a.z; v[3]=(bf16)a.w;
  v[4]=(bf16)b.x; v[5]=(bf16)b.y; v[6]=(bf16)b.z; v[7]=(bf16)b.w;
  *reinterpret_cast<bf16x8*>(xb + i) = v;
}

// ------- register-only 8x8 blockify: W [R][C] fp32 -> [(R/8)][C][8] bf16 -------
// elem (r,c) -> ((r>>3)*C + c)*8 + (r&7).  Reads 32B/lane coalesced, writes 128B/lane
// contiguous, no LDS. Gives the GEMM 8-contiguous-K blocks per N column.
__global__ __launch_bounds__(256) void k_blockify(const float* __restrict__ in,
                                                  bf16* __restrict__ out, int R, int C) {
  const float* src = in + (size_t)blockIdx.y * R * C;
  bf16* dst = out + (size_t)blockIdx.y * R * C;
  int flat = blockIdx.x * 256 + threadIdx.x;
  int CG = C >> 3;
  int cg = flat % CG;
  int rb = flat / CG;
  int c0 = cg * 8;
  size_t r0 = (size_t)rb * 8;
  float t[8][8];
#pragma unroll
  for (int j = 0; j < 8; ++j) {
    float4 v0 = *reinterpret_cast<const float4*>(src + (r0 + j) * C + c0);
    float4 v1 = *reinterpret_cast<const float4*>(src + (r0 + j) * C + c0 + 4);
    t[j][0]=v0.x; t[j][1]=v0.y; t[j][2]=v0.z; t[j][3]=v0.w;
    t[j][4]=v1.x; t[j][5]=v1.y; t[j][6]=v1.z; t[j][7]=v1.w;
  }
  bf16* d = dst + ((size_t)rb * C + c0) * 8;
#pragma unroll
  for (int ii = 0; ii < 8; ++ii) {
    bf16x8 o;
#pragma unroll
    for (int il = 0; il < 8; ++il) o[il] = (bf16)t[il][ii];
    *reinterpret_cast<bf16x8*>(d + ii * 8) = o;
  }
}

// ---------------- router: fp32 logits, softmax top-2, renormalized ----------------
__global__ __launch_bounds__(256) void k_router(const float* __restrict__ x,
                                                const float* __restrict__ Wr,
                                                int* __restrict__ ridx,
                                                float* __restrict__ rw,
                                                int* __restrict__ counts) {
  int lane = threadIdx.x & 63;
  int wid  = threadIdx.x >> 6;
  int t = blockIdx.x * 4 + wid;
  const float* xr = x + (size_t)t * H_DIM;
  float acc[E_NUM];
#pragma unroll
  for (int e = 0; e < E_NUM; ++e) acc[e] = 0.f;
  for (int h = lane; h < H_DIM; h += 64) {
    float xv = xr[h];
    const float* wr = Wr + h * E_NUM;
#pragma unroll
    for (int e = 0; e < E_NUM; ++e) acc[e] += xv * wr[e];
  }
#pragma unroll
  for (int off = 32; off > 0; off >>= 1) {
#pragma unroll
    for (int e = 0; e < E_NUM; ++e) acc[e] += __shfl_xor(acc[e], off);
  }
  if (lane == 0) {
    int i0 = 0;
#pragma unroll
    for (int e = 1; e < E_NUM; ++e) if (acc[e] > acc[i0]) i0 = e;
    int i1 = (i0 == 0) ? 1 : 0;
#pragma unroll
    for (int e = 0; e < E_NUM; ++e) if (e != i0 && acc[e] > acc[i1]) i1 = e;
    float r  = expf(acc[i1] - acc[i0]);
    float w0 = 1.f / (1.f + r);
    float w1 = r / (1.f + r);
    ridx[2 * t]     = i0;
    ridx[2 * t + 1] = i1;
    rw[2 * t]     = w0;
    rw[2 * t + 1] = w1;
    atomicAdd(&counts[i0], 1);
    atomicAdd(&counts[i1], 1);
  }
}

// ------- scan: counts -> offsets, compact tile list, zero cursors -------
__global__ void k_scan(const int* __restrict__ counts, int* __restrict__ offsets,
                       int* __restrict__ cursor, int* __restrict__ tiles,
                       int* __restrict__ n_tiles) {
  if (threadIdx.x == 0) {
    int s = 0, nt = 0;
    for (int e = 0; e < E_NUM; ++e) {
      offsets[e] = s;
      int c = counts[e];
      for (int pt = 0; pt * BM < c && nt < MAXTILE; ++pt) tiles[nt++] = (e << 16) | pt;
      s += c;
    }
    offsets[E_NUM] = s;
    *n_tiles = nt;
  }
  if (threadIdx.x < E_NUM) cursor[threadIdx.x] = 0;
}

// ---------------- scatter pair ids into expert-sorted perm ----------------
__global__ __launch_bounds__(256) void k_scatter(const int* __restrict__ ridx,
                                                 const int* __restrict__ offsets,
                                                 int* __restrict__ cursor,
                                                 int* __restrict__ perm) {
  int t = blockIdx.x * 256 + threadIdx.x;
  if (t >= T_TOK) return;
#pragma unroll
  for (int k = 0; k < 2; ++k) {
    int e = ridx[2 * t + k];
    int pos = atomicAdd(&cursor[e], 1);
    perm[offsets[e] + pos] = 2 * t + k;
  }
}

// ------- fused gate+up grouped GEMM: gload_lds from blockified W, 4 blocks/CU -------
__global__ __launch_bounds__(256, 4) void k_gateup(const bf16* __restrict__ xb,
                                                   const bf16* __restrict__ Wgb,
                                                   const bf16* __restrict__ Wub,
                                                   const int* __restrict__ perm,
                                                   const int* __restrict__ offsets,
                                                   const int* __restrict__ tiles,
                                                   const int* __restrict__ n_tiles,
                                                   bf16* __restrict__ hidden) {
  if ((int)blockIdx.y >= *n_tiles) return;
  int tv = tiles[blockIdx.y];
  int e = tv >> 16, pt = tv & 0xffff;
  int seg0 = offsets[e], cnt = offsets[e + 1] - seg0;
  int n0 = blockIdx.x * BN;

  __shared__ bf16 As[BM * BK];
  __shared__ bf16 Bg[BN * BK];
  __shared__ bf16 Bu[BN * BK];

  int tid = threadIdx.x, lane = tid & 63, wid = tid >> 6;
  int wm = wid >> 1, wn = wid & 1, l15 = lane & 15, l16 = lane >> 4;

  // staging chunks c in {tid, tid+256}: row=c>>2, slot=c&3 -> LDS elems [row*32 + slot*8, +8)
  int srow1 = tid >> 2, srow2 = 64 + srow1;
  int slot = tid & 3;
  int p1 = pt * BM + srow1, p2 = pt * BM + srow2;
  // A (x): row-major, 8 contiguous k at slot*8 within the row
  const bf16* a1 = xb + (size_t)(perm[seg0 + (p1 < cnt ? p1 : 0)] >> 1) * H_DIM + slot * 8;
  const bf16* a2 = xb + (size_t)(perm[seg0 + (p2 < cnt ? p2 : 0)] >> 1) * H_DIM + slot * 8;
  // B (W blockified): elem (k,n) at ((k>>3)*I + n)*8 + (k&7); chunk base = (slot*I + n)*8
  const bf16* g1 = Wgb + (size_t)e * H_DIM * I_DIM + ((size_t)slot * I_DIM + n0 + srow1) * 8;
  const bf16* g2 = Wgb + (size_t)e * H_DIM * I_DIM + ((size_t)slot * I_DIM + n0 + srow2) * 8;
  const bf16* u1 = Wub + (size_t)e * H_DIM * I_DIM + ((size_t)slot * I_DIM + n0 + srow1) * 8;
  const bf16* u2 = Wub + (size_t)e * H_DIM * I_DIM + ((size_t)slot * I_DIM + n0 + srow2) * 8;
  bf16* lA1 = &As[tid * 8];       bf16* lA2 = &As[2048 + tid * 8];
  bf16* lG1 = &Bg[tid * 8];       bf16* lG2 = &Bg[2048 + tid * 8];
  bf16* lU1 = &Bu[tid * 8];       bf16* lU2 = &Bu[2048 + tid * 8];

  f32x4 accg[4][4], accu[4][4];
#pragma unroll
  for (int m = 0; m < 4; ++m)
#pragma unroll
    for (int n = 0; n < 4; ++n) {
      accg[m][n] = (f32x4){0.f, 0.f, 0.f, 0.f};
      accu[m][n] = (f32x4){0.f, 0.f, 0.f, 0.f};
    }

  for (int k0 = 0; k0 < H_DIM; k0 += BK) {
    size_t wk = (size_t)k0 * I_DIM;        // B-side K-step stride in blockified layout
    GL16(a1 + k0, lA1);  GL16(a2 + k0, lA2);
    GL16(g1 + wk, lG1);  GL16(g2 + wk, lG2);
    GL16(u1 + wk, lU1);  GL16(u2 + wk, lU2);
    __syncthreads();                 // drains vmcnt -> LDS tiles ready

    bf16x8 af[4], bg[4], bu[4];
#pragma unroll
    for (int m = 0; m < 4; ++m)
      af[m] = *reinterpret_cast<const bf16x8*>(&As[(wm * 64 + m * 16 + l15) * BK + l16 * 8]);
#pragma unroll
    for (int n = 0; n < 4; ++n) {
      bg[n] = *reinterpret_cast<const bf16x8*>(&Bg[(wn * 64 + n * 16 + l15) * BK + l16 * 8]);
      bu[n] = *reinterpret_cast<const bf16x8*>(&Bu[(wn * 64 + n * 16 + l15) * BK + l16 * 8]);
    }
#pragma unroll
    for (int m = 0; m < 4; ++m)
#pragma unroll
      for (int n = 0; n < 4; ++n) {
        accg[m][n] = __builtin_amdgcn_mfma_f32_16x16x32_bf16(af[m], bg[n], accg[m][n], 0, 0, 0);
        accu[m][n] = __builtin_amdgcn_mfma_f32_16x16x32_bf16(af[m], bu[n], accu[m][n], 0, 0, 0);
      }
    __syncthreads();
  }

#pragma unroll
  for (int m = 0; m < 4; ++m) {
#pragma unroll
    for (int r = 0; r < 4; ++r) {
      int p_glob = pt * BM + wm * 64 + m * 16 + l16 * 4 + r;
      if (p_glob < cnt) {
        bf16* hrow = hidden + (size_t)(seg0 + p_glob) * I_DIM;
#pragma unroll
        for (int n = 0; n < 4; ++n) {
          int col = n0 + wn * 64 + n * 16 + l15;
          float g = accg[m][n][r];
          float u = accu[m][n][r];
          float h = g / (1.f + __expf(-g)) * u;
          hrow[col] = (bf16)h;
        }
      }
    }
  }
}

// ------- down grouped GEMM: gload_lds from blockified Wd, 4 blocks/CU -------
__global__ __launch_bounds__(256, 4) void k_down(const bf16* __restrict__ hidden,
                                                 const bf16* __restrict__ Wdb,
                                                 const int* __restrict__ perm,
                                                 const int* __restrict__ offsets,
                                                 const int* __restrict__ tiles,
                                                 const int* __restrict__ n_tiles,
                                                 float* __restrict__ pair_out) {
  if ((int)blockIdx.y >= *n_tiles) return;
  int tv = tiles[blockIdx.y];
  int e = tv >> 16, pt = tv & 0xffff;
  int seg0 = offsets[e], cnt = offsets[e + 1] - seg0;
  int n0 = blockIdx.x * BN;

  __shared__ bf16 As[BM * BK];
  __shared__ bf16 Bs[BN * BK];

  int tid = threadIdx.x, lane = tid & 63, wid = tid >> 6;
  int wm = wid >> 1, wn = wid & 1, l15 = lane & 15, l16 = lane >> 4;

  int srow1 = tid >> 2, srow2 = 64 + srow1;
  int slot = tid & 3;
  int p1 = pt * BM + srow1, p2 = pt * BM + srow2;
  const bf16* a1 = hidden + (size_t)(seg0 + (p1 < cnt ? p1 : 0)) * I_DIM + slot * 8;
  const bf16* a2 = hidden + (size_t)(seg0 + (p2 < cnt ? p2 : 0)) * I_DIM + slot * 8;
  // Wd blockified: elem (k=i, n=h) at ((k>>3)*H + n)*8 + (k&7)
  const bf16* b1 = Wdb + (size_t)e * I_DIM * H_DIM + ((size_t)slot * H_DIM + n0 + srow1) * 8;
  const bf16* b2 = Wdb + (size_t)e * I_DIM * H_DIM + ((size_t)slot * H_DIM + n0 + srow2) * 8;
  bf16* lA1 = &As[tid * 8];  bf16* lA2 = &As[2048 + tid * 8];
  bf16* lB1 = &Bs[tid * 8];  bf16* lB2 = &Bs[2048 + tid * 8];

  f32x4 acc[4][4];
#pragma unroll
  for (int m = 0; m < 4; ++m)
#pragma unroll
    for (int n = 0; n < 4; ++n) acc[m][n] = (f32x4){0.f, 0.f, 0.f, 0.f};

  for (int k0 = 0; k0 < I_DIM; k0 += BK) {
    size_t wk = (size_t)k0 * H_DIM;
    GL16(a1 + k0, lA1);  GL16(a2 + k0, lA2);
    GL16(b1 + wk, lB1);  GL16(b2 + wk, lB2);
    __syncthreads();

    bf16x8 af[4], bfr[4];
#pragma unroll
    for (int m = 0; m < 4; ++m)
      af[m] = *reinterpret_cast<const bf16x8*>(&As[(wm * 64 + m * 16 + l15) * BK + l16 * 8]);
#pragma unroll
    for (int n = 0; n < 4; ++n)
      bfr[n] = *reinterpret_cast<const bf16x8*>(&Bs[(wn * 64 + n * 16 + l15) * BK + l16 * 8]);
#pragma unroll
    for (int m = 0; m < 4; ++m)
#pragma unroll
      for (int n = 0; n < 4; ++n)
        acc[m][n] = __builtin_amdgcn_mfma_f32_16x16x32_bf16(af[m], bfr[n], acc[m][n], 0, 0, 0);
    __syncthreads();
  }

#pragma unroll
  for (int m = 0; m < 4; ++m) {
#pragma unroll
    for (int r = 0; r < 4; ++r) {
      int p_glob = pt * BM + wm * 64 + m * 16 + l16 * 4 + r;
      if (p_glob < cnt) {
        int pair = perm[seg0 + p_glob];
        float* orow = pair_out + (size_t)pair * H_DIM;
#pragma unroll
        for (int n = 0; n < 4; ++n) {
          int col = n0 + wn * 64 + n * 16 + l15;
          orow[col] = acc[m][n][r];
        }
      }
    }
  }
}

// ---------------- combine ----------------
__global__ __launch_bounds__(256) void k_combine(const float* __restrict__ pair_out,
                                                 const float* __restrict__ rw,
                                                 float* __restrict__ out) {
  int t = blockIdx.x;
  int c = threadIdx.x;
  float w0 = rw[2 * t];
  float w1 = rw[2 * t + 1];
  float4 a = *reinterpret_cast<const float4*>(pair_out + ((size_t)(2 * t)) * H_DIM + c * 4);
  float4 b = *reinterpret_cast<const float4*>(pair_out + ((size_t)(2 * t + 1)) * H_DIM + c * 4);
  float4 o;
  o.x = w0 * a.x + w1 * b.x;
  o.y = w0 * a.y + w1 * b.y;
  o.z = w0 * a.z + w1 * b.z;
  o.w = w0 * a.w + w1 * b.w;
  *reinterpret_cast<float4*>(out + (size_t)t * H_DIM + c * 4) = o;
}

extern "C" void kernel_launch(void* const* d_in, const int* in_sizes, int n_in,
                              void* d_out, int out_size, void* d_ws, size_t ws_size,
                              hipStream_t stream) {
  const float* x  = (const float*)d_in[0];
  const float* Wr = (const float*)d_in[1];
  const float* Wg = (const float*)d_in[2];
  const float* Wu = (const float*)d_in[3];
  const float* Wd = (const float*)d_in[4];
  float* out = (float*)d_out;

  char* ws = (char*)d_ws;
  int*   counts  = (int*)(ws);
  int*   cursor  = (int*)(ws + 256);
  int*   offsets = (int*)(ws + 512);
  int*   n_tiles = (int*)(ws + 768);
  int*   tiles   = (int*)(ws + 1024);
  int*   ridx    = (int*)(ws + 64 * 1024);
  float* rw      = (float*)(ws + 128 * 1024);
  int*   perm    = (int*)(ws + 192 * 1024);
  bf16*  xb      = (bf16*)(ws + (1ull << 20));
  bf16*  Wgb     = (bf16*)(ws + (16ull << 20));
  bf16*  Wub     = (bf16*)(ws + (66ull << 20));
  bf16*  Wdb     = (bf16*)(ws + (116ull << 20));
  bf16*  hidden  = (bf16*)(ws + (166ull << 20));
  float* pair_out = (float*)(ws + (212ull << 20));

  // per-expert 8x8-block work-items: (1024/8)*(2816/8) = 45056 = 176 * 256
  constexpr int BLK_BLOCKS = 176;

  hipMemsetAsync(counts, 0, 64, stream);
  k_xcast<<<dim3(T_TOK * H_DIM / 2048), dim3(256), 0, stream>>>(x, xb);
  k_blockify<<<dim3(BLK_BLOCKS, E_NUM), dim3(256), 0, stream>>>(Wg, Wgb, H_DIM, I_DIM);
  k_blockify<<<dim3(BLK_BLOCKS, E_NUM), dim3(256), 0, stream>>>(Wu, Wub, H_DIM, I_DIM);
  k_blockify<<<dim3(BLK_BLOCKS, E_NUM), dim3(256), 0, stream>>>(Wd, Wdb, I_DIM, H_DIM);
  k_router<<<dim3(T_TOK / 4), dim3(256), 0, stream>>>(x, Wr, ridx, rw, counts);
  k_scan<<<dim3(1), dim3(64), 0, stream>>>(counts, offsets, cursor, tiles, n_tiles);
  k_scatter<<<dim3((T_TOK + 255) / 256), dim3(256), 0, stream>>>(ridx, offsets, cursor, perm);
  k_gateup<<<dim3(I_DIM / BN, MAXTILE), dim3(256), 0, stream>>>(
      xb, Wgb, Wub, perm, offsets, tiles, n_tiles, hidden);
  k_down<<<dim3(H_DIM / BN, MAXTILE), dim3(256), 0, stream>>>(
      hidden, Wdb, perm, offsets, tiles, n_tiles, pair_out);
  k_combine<<<dim3(T_TOK), dim3(256), 0, stream>>>(pair_out, rw, out);
}

// Round 9
// 558.092 us; speedup vs baseline: 2.4437x; 2.4437x over previous
//
#include <hip/hip_runtime.h>
#include <cstdint>
#include <cstddef>

#define T_TOK 4096
#define H_DIM 1024
#define I_DIM 2816
#define E_NUM 9
#define MAXTILE 76

typedef __bf16 bf16;
typedef bf16 bf16x8 __attribute__((ext_vector_type(8)));
typedef float f32x4 __attribute__((ext_vector_type(4)));

constexpr int BM = 128, BN = 128, BK = 32;

// async global->LDS, 16B per lane; LDS dest must be linear (wave-uniform base + lane*16)
#define GL16(gp, lp)                                                                   \
  __builtin_amdgcn_global_load_lds((const __attribute__((address_space(1))) void*)(gp), \
                                   (__attribute__((address_space(3))) void*)(lp), 16, 0, 0)

// ---------------- x: fp32 -> bf16 ----------------
__global__ __launch_bounds__(256) void k_xcast(const float* __restrict__ x, bf16* __restrict__ xb) {
  size_t i = ((size_t)blockIdx.x * 256 + threadIdx.x) * 8;
  float4 a = *reinterpret_cast<const float4*>(x + i);
  float4 b = *reinterpret_cast<const float4*>(x + i + 4);
  bf16x8 v;
  v[0]=(bf16)a.x; v[1]=(bf16)a.y; v[2]=(bf16)a.z; v[3]=(bf16)a.w;
  v[4]=(bf16)b.x; v[5]=(bf16)b.y; v[6]=(bf16)b.z; v[7]=(bf16)b.w;
  *reinterpret_cast<bf16x8*>(xb + i) = v;
}

// ------- register-only 8x8 blockify: W [R][C] fp32 -> [(R/8)][C][8] bf16 -------
// elem (r,c) -> ((r>>3)*C + c)*8 + (r&7).  Reads 32B/lane coalesced, writes 128B/lane
// contiguous, no LDS.
__global__ __launch_bounds__(256) void k_blockify(const float* __restrict__ in,
                                                  bf16* __restrict__ out, int R, int C) {
  const float* src = in + (size_t)blockIdx.y * R * C;
  bf16* dst = out + (size_t)blockIdx.y * R * C;
  int flat = blockIdx.x * 256 + threadIdx.x;
  int CG = C >> 3;
  int cg = flat % CG;
  int rb = flat / CG;
  int c0 = cg * 8;
  size_t r0 = (size_t)rb * 8;
  float t[8][8];
#pragma unroll
  for (int j = 0; j < 8; ++j) {
    float4 v0 = *reinterpret_cast<const float4*>(src + (r0 + j) * C + c0);
    float4 v1 = *reinterpret_cast<const float4*>(src + (r0 + j) * C + c0 + 4);
    t[j][0]=v0.x; t[j][1]=v0.y; t[j][2]=v0.z; t[j][3]=v0.w;
    t[j][4]=v1.x; t[j][5]=v1.y; t[j][6]=v1.z; t[j][7]=v1.w;
  }
  bf16* d = dst + ((size_t)rb * C + c0) * 8;
#pragma unroll
  for (int ii = 0; ii < 8; ++ii) {
    bf16x8 o;
#pragma unroll
    for (int il = 0; il < 8; ++il) o[il] = (bf16)t[il][ii];
    *reinterpret_cast<bf16x8*>(d + ii * 8) = o;
  }
}

// ---------------- router: fp32 logits, softmax top-2, renormalized ----------------
__global__ __launch_bounds__(256) void k_router(const float* __restrict__ x,
                                                const float* __restrict__ Wr,
                                                int* __restrict__ ridx,
                                                float* __restrict__ rw,
                                                int* __restrict__ counts) {
  int lane = threadIdx.x & 63;
  int wid  = threadIdx.x >> 6;
  int t = blockIdx.x * 4 + wid;
  const float* xr = x + (size_t)t * H_DIM;
  float acc[E_NUM];
#pragma unroll
  for (int e = 0; e < E_NUM; ++e) acc[e] = 0.f;
  for (int h = lane; h < H_DIM; h += 64) {
    float xv = xr[h];
    const float* wr = Wr + h * E_NUM;
#pragma unroll
    for (int e = 0; e < E_NUM; ++e) acc[e] += xv * wr[e];
  }
#pragma unroll
  for (int off = 32; off > 0; off >>= 1) {
#pragma unroll
    for (int e = 0; e < E_NUM; ++e) acc[e] += __shfl_xor(acc[e], off);
  }
  if (lane == 0) {
    int i0 = 0;
#pragma unroll
    for (int e = 1; e < E_NUM; ++e) if (acc[e] > acc[i0]) i0 = e;
    int i1 = (i0 == 0) ? 1 : 0;
#pragma unroll
    for (int e = 0; e < E_NUM; ++e) if (e != i0 && acc[e] > acc[i1]) i1 = e;
    float r  = expf(acc[i1] - acc[i0]);
    float w0 = 1.f / (1.f + r);
    float w1 = r / (1.f + r);
    ridx[2 * t]     = i0;
    ridx[2 * t + 1] = i1;
    rw[2 * t]     = w0;
    rw[2 * t + 1] = w1;
    atomicAdd(&counts[i0], 1);
    atomicAdd(&counts[i1], 1);
  }
}

// ------- scan: counts -> offsets, compact tile list, zero cursors -------
__global__ void k_scan(const int* __restrict__ counts, int* __restrict__ offsets,
                       int* __restrict__ cursor, int* __restrict__ tiles,
                       int* __restrict__ n_tiles) {
  if (threadIdx.x == 0) {
    int s = 0, nt = 0;
    for (int e = 0; e < E_NUM; ++e) {
      offsets[e] = s;
      int c = counts[e];
      for (int pt = 0; pt * BM < c && nt < MAXTILE; ++pt) tiles[nt++] = (e << 16) | pt;
      s += c;
    }
    offsets[E_NUM] = s;
    *n_tiles = nt;
  }
  if (threadIdx.x < E_NUM) cursor[threadIdx.x] = 0;
}

// ---------------- scatter pair ids into expert-sorted perm ----------------
__global__ __launch_bounds__(256) void k_scatter(const int* __restrict__ ridx,
                                                 const int* __restrict__ offsets,
                                                 int* __restrict__ cursor,
                                                 int* __restrict__ perm) {
  int t = blockIdx.x * 256 + threadIdx.x;
  if (t >= T_TOK) return;
#pragma unroll
  for (int k = 0; k < 2; ++k) {
    int e = ridx[2 * t + k];
    int pos = atomicAdd(&cursor[e], 1);
    perm[offsets[e] + pos] = 2 * t + k;
  }
}

// ------- fused gate+up grouped GEMM: gload_lds from blockified W (2 blocks/CU) -------
// NOTE: accumulators need 128 regs; launch_bounds(256,2) is the occupancy cliff edge —
// (256,4) forced unified VGPR+AGPR<=128 and spilled acc to scratch (round-8: 4.2GB HBM).
__global__ __launch_bounds__(256, 2) void k_gateup(const bf16* __restrict__ xb,
                                                   const bf16* __restrict__ Wgb,
                                                   const bf16* __restrict__ Wub,
                                                   const int* __restrict__ perm,
                                                   const int* __restrict__ offsets,
                                                   const int* __restrict__ tiles,
                                                   const int* __restrict__ n_tiles,
                                                   bf16* __restrict__ hidden) {
  if ((int)blockIdx.y >= *n_tiles) return;
  int tv = tiles[blockIdx.y];
  int e = tv >> 16, pt = tv & 0xffff;
  int seg0 = offsets[e], cnt = offsets[e + 1] - seg0;
  int n0 = blockIdx.x * BN;

  __shared__ bf16 As[BM * BK];
  __shared__ bf16 Bg[BN * BK];
  __shared__ bf16 Bu[BN * BK];

  int tid = threadIdx.x, lane = tid & 63, wid = tid >> 6;
  int wm = wid >> 1, wn = wid & 1, l15 = lane & 15, l16 = lane >> 4;

  int srow1 = tid >> 2, srow2 = 64 + srow1;
  int slot = tid & 3;
  int p1 = pt * BM + srow1, p2 = pt * BM + srow2;
  const bf16* a1 = xb + (size_t)(perm[seg0 + (p1 < cnt ? p1 : 0)] >> 1) * H_DIM + slot * 8;
  const bf16* a2 = xb + (size_t)(perm[seg0 + (p2 < cnt ? p2 : 0)] >> 1) * H_DIM + slot * 8;
  const bf16* g1 = Wgb + (size_t)e * H_DIM * I_DIM + ((size_t)slot * I_DIM + n0 + srow1) * 8;
  const bf16* g2 = Wgb + (size_t)e * H_DIM * I_DIM + ((size_t)slot * I_DIM + n0 + srow2) * 8;
  const bf16* u1 = Wub + (size_t)e * H_DIM * I_DIM + ((size_t)slot * I_DIM + n0 + srow1) * 8;
  const bf16* u2 = Wub + (size_t)e * H_DIM * I_DIM + ((size_t)slot * I_DIM + n0 + srow2) * 8;
  bf16* lA1 = &As[tid * 8];       bf16* lA2 = &As[2048 + tid * 8];
  bf16* lG1 = &Bg[tid * 8];       bf16* lG2 = &Bg[2048 + tid * 8];
  bf16* lU1 = &Bu[tid * 8];       bf16* lU2 = &Bu[2048 + tid * 8];

  f32x4 accg[4][4], accu[4][4];
#pragma unroll
  for (int m = 0; m < 4; ++m)
#pragma unroll
    for (int n = 0; n < 4; ++n) {
      accg[m][n] = (f32x4){0.f, 0.f, 0.f, 0.f};
      accu[m][n] = (f32x4){0.f, 0.f, 0.f, 0.f};
    }

  for (int k0 = 0; k0 < H_DIM; k0 += BK) {
    size_t wk = (size_t)k0 * I_DIM;        // B-side K-step stride in blockified layout
    GL16(a1 + k0, lA1);  GL16(a2 + k0, lA2);
    GL16(g1 + wk, lG1);  GL16(g2 + wk, lG2);
    GL16(u1 + wk, lU1);  GL16(u2 + wk, lU2);
    __syncthreads();                 // drains vmcnt -> LDS tiles ready

    bf16x8 af[4], bg[4], bu[4];
#pragma unroll
    for (int m = 0; m < 4; ++m)
      af[m] = *reinterpret_cast<const bf16x8*>(&As[(wm * 64 + m * 16 + l15) * BK + l16 * 8]);
#pragma unroll
    for (int n = 0; n < 4; ++n) {
      bg[n] = *reinterpret_cast<const bf16x8*>(&Bg[(wn * 64 + n * 16 + l15) * BK + l16 * 8]);
      bu[n] = *reinterpret_cast<const bf16x8*>(&Bu[(wn * 64 + n * 16 + l15) * BK + l16 * 8]);
    }
#pragma unroll
    for (int m = 0; m < 4; ++m)
#pragma unroll
      for (int n = 0; n < 4; ++n) {
        accg[m][n] = __builtin_amdgcn_mfma_f32_16x16x32_bf16(af[m], bg[n], accg[m][n], 0, 0, 0);
        accu[m][n] = __builtin_amdgcn_mfma_f32_16x16x32_bf16(af[m], bu[n], accu[m][n], 0, 0, 0);
      }
    __syncthreads();
  }

#pragma unroll
  for (int m = 0; m < 4; ++m) {
#pragma unroll
    for (int r = 0; r < 4; ++r) {
      int p_glob = pt * BM + wm * 64 + m * 16 + l16 * 4 + r;
      if (p_glob < cnt) {
        bf16* hrow = hidden + (size_t)(seg0 + p_glob) * I_DIM;
#pragma unroll
        for (int n = 0; n < 4; ++n) {
          int col = n0 + wn * 64 + n * 16 + l15;
          float g = accg[m][n][r];
          float u = accu[m][n][r];
          float h = g / (1.f + __expf(-g)) * u;
          hrow[col] = (bf16)h;
        }
      }
    }
  }
}

// ------- down grouped GEMM: gload_lds from blockified Wd (2 blocks/CU) -------
__global__ __launch_bounds__(256, 2) void k_down(const bf16* __restrict__ hidden,
                                                 const bf16* __restrict__ Wdb,
                                                 const int* __restrict__ perm,
                                                 const int* __restrict__ offsets,
                                                 const int* __restrict__ tiles,
                                                 const int* __restrict__ n_tiles,
                                                 float* __restrict__ pair_out) {
  if ((int)blockIdx.y >= *n_tiles) return;
  int tv = tiles[blockIdx.y];
  int e = tv >> 16, pt = tv & 0xffff;
  int seg0 = offsets[e], cnt = offsets[e + 1] - seg0;
  int n0 = blockIdx.x * BN;

  __shared__ bf16 As[BM * BK];
  __shared__ bf16 Bs[BN * BK];

  int tid = threadIdx.x, lane = tid & 63, wid = tid >> 6;
  int wm = wid >> 1, wn = wid & 1, l15 = lane & 15, l16 = lane >> 4;

  int srow1 = tid >> 2, srow2 = 64 + srow1;
  int slot = tid & 3;
  int p1 = pt * BM + srow1, p2 = pt * BM + srow2;
  const bf16* a1 = hidden + (size_t)(seg0 + (p1 < cnt ? p1 : 0)) * I_DIM + slot * 8;
  const bf16* a2 = hidden + (size_t)(seg0 + (p2 < cnt ? p2 : 0)) * I_DIM + slot * 8;
  const bf16* b1 = Wdb + (size_t)e * I_DIM * H_DIM + ((size_t)slot * H_DIM + n0 + srow1) * 8;
  const bf16* b2 = Wdb + (size_t)e * I_DIM * H_DIM + ((size_t)slot * H_DIM + n0 + srow2) * 8;
  bf16* lA1 = &As[tid * 8];  bf16* lA2 = &As[2048 + tid * 8];
  bf16* lB1 = &Bs[tid * 8];  bf16* lB2 = &Bs[2048 + tid * 8];

  f32x4 acc[4][4];
#pragma unroll
  for (int m = 0; m < 4; ++m)
#pragma unroll
    for (int n = 0; n < 4; ++n) acc[m][n] = (f32x4){0.f, 0.f, 0.f, 0.f};

  for (int k0 = 0; k0 < I_DIM; k0 += BK) {
    size_t wk = (size_t)k0 * H_DIM;
    GL16(a1 + k0, lA1);  GL16(a2 + k0, lA2);
    GL16(b1 + wk, lB1);  GL16(b2 + wk, lB2);
    __syncthreads();

    bf16x8 af[4], bfr[4];
#pragma unroll
    for (int m = 0; m < 4; ++m)
      af[m] = *reinterpret_cast<const bf16x8*>(&As[(wm * 64 + m * 16 + l15) * BK + l16 * 8]);
#pragma unroll
    for (int n = 0; n < 4; ++n)
      bfr[n] = *reinterpret_cast<const bf16x8*>(&Bs[(wn * 64 + n * 16 + l15) * BK + l16 * 8]);
#pragma unroll
    for (int m = 0; m < 4; ++m)
#pragma unroll
      for (int n = 0; n < 4; ++n)
        acc[m][n] = __builtin_amdgcn_mfma_f32_16x16x32_bf16(af[m], bfr[n], acc[m][n], 0, 0, 0);
    __syncthreads();
  }

#pragma unroll
  for (int m = 0; m < 4; ++m) {
#pragma unroll
    for (int r = 0; r < 4; ++r) {
      int p_glob = pt * BM + wm * 64 + m * 16 + l16 * 4 + r;
      if (p_glob < cnt) {
        int pair = perm[seg0 + p_glob];
        float* orow = pair_out + (size_t)pair * H_DIM;
#pragma unroll
        for (int n = 0; n < 4; ++n) {
          int col = n0 + wn * 64 + n * 16 + l15;
          orow[col] = acc[m][n][r];
        }
      }
    }
  }
}

// ---------------- combine ----------------
__global__ __launch_bounds__(256) void k_combine(const float* __restrict__ pair_out,
                                                 const float* __restrict__ rw,
                                                 float* __restrict__ out) {
  int t = blockIdx.x;
  int c = threadIdx.x;
  float w0 = rw[2 * t];
  float w1 = rw[2 * t + 1];
  float4 a = *reinterpret_cast<const float4*>(pair_out + ((size_t)(2 * t)) * H_DIM + c * 4);
  float4 b = *reinterpret_cast<const float4*>(pair_out + ((size_t)(2 * t + 1)) * H_DIM + c * 4);
  float4 o;
  o.x = w0 * a.x + w1 * b.x;
  o.y = w0 * a.y + w1 * b.y;
  o.z = w0 * a.z + w1 * b.z;
  o.w = w0 * a.w + w1 * b.w;
  *reinterpret_cast<float4*>(out + (size_t)t * H_DIM + c * 4) = o;
}

extern "C" void kernel_launch(void* const* d_in, const int* in_sizes, int n_in,
                              void* d_out, int out_size, void* d_ws, size_t ws_size,
                              hipStream_t stream) {
  const float* x  = (const float*)d_in[0];
  const float* Wr = (const float*)d_in[1];
  const float* Wg = (const float*)d_in[2];
  const float* Wu = (const float*)d_in[3];
  const float* Wd = (const float*)d_in[4];
  float* out = (float*)d_out;

  char* ws = (char*)d_ws;
  int*   counts  = (int*)(ws);
  int*   cursor  = (int*)(ws + 256);
  int*   offsets = (int*)(ws + 512);
  int*   n_tiles = (int*)(ws + 768);
  int*   tiles   = (int*)(ws + 1024);
  int*   ridx    = (int*)(ws + 64 * 1024);
  float* rw      = (float*)(ws + 128 * 1024);
  int*   perm    = (int*)(ws + 192 * 1024);
  bf16*  xb      = (bf16*)(ws + (1ull << 20));
  bf16*  Wgb     = (bf16*)(ws + (16ull << 20));
  bf16*  Wub     = (bf16*)(ws + (66ull << 20));
  bf16*  Wdb     = (bf16*)(ws + (116ull << 20));
  bf16*  hidden  = (bf16*)(ws + (166ull << 20));
  float* pair_out = (float*)(ws + (212ull << 20));

  constexpr int BLK_BLOCKS = 176;   // (1024/8)*(2816/8) / 256

  hipMemsetAsync(counts, 0, 64, stream);
  k_xcast<<<dim3(T_TOK * H_DIM / 2048), dim3(256), 0, stream>>>(x, xb);
  k_blockify<<<dim3(BLK_BLOCKS, E_NUM), dim3(256), 0, stream>>>(Wg, Wgb, H_DIM, I_DIM);
  k_blockify<<<dim3(BLK_BLOCKS, E_NUM), dim3(256), 0, stream>>>(Wu, Wub, H_DIM, I_DIM);
  k_blockify<<<dim3(BLK_BLOCKS, E_NUM), dim3(256), 0, stream>>>(Wd, Wdb, I_DIM, H_DIM);
  k_router<<<dim3(T_TOK / 4), dim3(256), 0, stream>>>(x, Wr, ridx, rw, counts);
  k_scan<<<dim3(1), dim3(64), 0, stream>>>(counts, offsets, cursor, tiles, n_tiles);
  k_scatter<<<dim3((T_TOK + 255) / 256), dim3(256), 0, stream>>>(ridx, offsets, cursor, perm);
  k_gateup<<<dim3(I_DIM / BN, MAXTILE), dim3(256), 0, stream>>>(
      xb, Wgb, Wub, perm, offsets, tiles, n_tiles, hidden);
  k_down<<<dim3(H_DIM / BN, MAXTILE), dim3(256), 0, stream>>>(
      hidden, Wdb, perm, offsets, tiles, n_tiles, pair_out);
  k_combine<<<dim3(T_TOK), dim3(256), 0, stream>>>(pair_out, rw, out);
}

// Round 10
// 510.487 us; speedup vs baseline: 2.6716x; 1.0933x over previous
//
#include <hip/hip_runtime.h>
#include <cstdint>
#include <cstddef>

#define T_TOK 4096
#define H_DIM 1024
#define I_DIM 2816
#define E_NUM 9
#define MAXTILE 76     // BM=128 tiles: 8192/128 + 9 partials max
#define MAXT64 137     // BM=64 tiles: 8192/64 + 9 partials max

typedef __bf16 bf16;
typedef bf16 bf16x4 __attribute__((ext_vector_type(4)));
typedef bf16 bf16x8 __attribute__((ext_vector_type(8)));
typedef float f32x4 __attribute__((ext_vector_type(4)));

constexpr int BM = 128, BN = 128, BK = 32;

// async global->LDS, 16B per lane; LDS dest must be linear (wave-uniform base + lane*16)
#define GL16(gp, lp)                                                                   \
  __builtin_amdgcn_global_load_lds((const __attribute__((address_space(1))) void*)(gp), \
                                   (__attribute__((address_space(3))) void*)(lp), 16, 0, 0)

// ---------------- x: fp32 -> bf16 ----------------
__global__ __launch_bounds__(256) void k_xcast(const float* __restrict__ x, bf16* __restrict__ xb) {
  size_t i = ((size_t)blockIdx.x * 256 + threadIdx.x) * 8;
  float4 a = *reinterpret_cast<const float4*>(x + i);
  float4 b = *reinterpret_cast<const float4*>(x + i + 4);
  bf16x8 v;
  v[0]=(bf16)a.x; v[1]=(bf16)a.y; v[2]=(bf16)a.z; v[3]=(bf16)a.w;
  v[4]=(bf16)b.x; v[5]=(bf16)b.y; v[6]=(bf16)b.z; v[7]=(bf16)b.w;
  *reinterpret_cast<bf16x8*>(xb + i) = v;
}

// ------- per-expert transpose+convert: in [R][C] fp32 -> out [C][R] bf16 -------
__global__ __launch_bounds__(256) void k_transpose(const float* __restrict__ in,
                                                   bf16* __restrict__ out, int R, int C) {
  const float* src = in + (size_t)blockIdx.z * R * C;
  bf16* dst = out + (size_t)blockIdx.z * R * C;
  __shared__ bf16 tile[64][72];
  int r0 = blockIdx.y * 64, c0 = blockIdx.x * 64;
  int t = threadIdx.x;
  int tr = t >> 4, tc = (t & 15) * 4;
#pragma unroll
  for (int it = 0; it < 4; ++it) {
    int r = tr + it * 16;
    float4 v = *reinterpret_cast<const float4*>(src + (size_t)(r0 + r) * C + c0 + tc);
    bf16x4 w; w[0]=(bf16)v.x; w[1]=(bf16)v.y; w[2]=(bf16)v.z; w[3]=(bf16)v.w;
    *reinterpret_cast<bf16x4*>(&tile[r][tc]) = w;
  }
  __syncthreads();
#pragma unroll
  for (int it = 0; it < 4; ++it) {
    int oc = tr + it * 16;
    bf16x4 w;
    w[0] = tile[tc + 0][oc]; w[1] = tile[tc + 1][oc];
    w[2] = tile[tc + 2][oc]; w[3] = tile[tc + 3][oc];
    *reinterpret_cast<bf16x4*>(dst + (size_t)(c0 + oc) * R + r0 + tc) = w;
  }
}

// ---------------- router: fp32 logits, softmax top-2, renormalized ----------------
__global__ __launch_bounds__(256) void k_router(const float* __restrict__ x,
                                                const float* __restrict__ Wr,
                                                int* __restrict__ ridx,
                                                float* __restrict__ rw,
                                                int* __restrict__ counts) {
  int lane = threadIdx.x & 63;
  int wid  = threadIdx.x >> 6;
  int t = blockIdx.x * 4 + wid;
  const float* xr = x + (size_t)t * H_DIM;
  float acc[E_NUM];
#pragma unroll
  for (int e = 0; e < E_NUM; ++e) acc[e] = 0.f;
  for (int h = lane; h < H_DIM; h += 64) {
    float xv = xr[h];
    const float* wr = Wr + h * E_NUM;
#pragma unroll
    for (int e = 0; e < E_NUM; ++e) acc[e] += xv * wr[e];
  }
#pragma unroll
  for (int off = 32; off > 0; off >>= 1) {
#pragma unroll
    for (int e = 0; e < E_NUM; ++e) acc[e] += __shfl_xor(acc[e], off);
  }
  if (lane == 0) {
    int i0 = 0;
#pragma unroll
    for (int e = 1; e < E_NUM; ++e) if (acc[e] > acc[i0]) i0 = e;
    int i1 = (i0 == 0) ? 1 : 0;
#pragma unroll
    for (int e = 0; e < E_NUM; ++e) if (e != i0 && acc[e] > acc[i1]) i1 = e;
    float r  = expf(acc[i1] - acc[i0]);
    float w0 = 1.f / (1.f + r);
    float w1 = r / (1.f + r);
    ridx[2 * t]     = i0;
    ridx[2 * t + 1] = i1;
    rw[2 * t]     = w0;
    rw[2 * t + 1] = w1;
    atomicAdd(&counts[i0], 1);
    atomicAdd(&counts[i1], 1);
  }
}

// ------- scan: counts -> offsets, two tile lists (BM=128 and BM=64), zero cursors -------
__global__ void k_scan(const int* __restrict__ counts, int* __restrict__ offsets,
                       int* __restrict__ cursor, int* __restrict__ tiles,
                       int* __restrict__ tiles64, int* __restrict__ n_tiles) {
  if (threadIdx.x == 0) {
    int s = 0, nt = 0, nt64 = 0;
    for (int e = 0; e < E_NUM; ++e) {
      offsets[e] = s;
      int c = counts[e];
      for (int pt = 0; pt * BM < c && nt < MAXTILE; ++pt) tiles[nt++] = (e << 16) | pt;
      for (int pt = 0; pt * 64 < c && nt64 < MAXT64; ++pt) tiles64[nt64++] = (e << 16) | pt;
      s += c;
    }
    offsets[E_NUM] = s;
    n_tiles[0] = nt;
    n_tiles[1] = nt64;
  }
  if (threadIdx.x < E_NUM) cursor[threadIdx.x] = 0;
}

// ---------------- scatter pair ids into expert-sorted perm ----------------
__global__ __launch_bounds__(256) void k_scatter(const int* __restrict__ ridx,
                                                 const int* __restrict__ offsets,
                                                 int* __restrict__ cursor,
                                                 int* __restrict__ perm) {
  int t = blockIdx.x * 256 + threadIdx.x;
  if (t >= T_TOK) return;
#pragma unroll
  for (int k = 0; k < 2; ++k) {
    int e = ridx[2 * t + k];
    int pos = atomicAdd(&cursor[e], 1);
    perm[offsets[e] + pos] = 2 * t + k;
  }
}

// ------- fused gate+up grouped GEMM: round-3 proven structure (163 us) -------
__global__ __launch_bounds__(256, 2) void k_gateup(const bf16* __restrict__ xb,
                                                   const bf16* __restrict__ WgT,
                                                   const bf16* __restrict__ WuT,
                                                   const int* __restrict__ perm,
                                                   const int* __restrict__ offsets,
                                                   const int* __restrict__ tiles,
                                                   const int* __restrict__ n_tiles,
                                                   bf16* __restrict__ hidden) {
  if ((int)blockIdx.y >= n_tiles[0]) return;
  int tv = tiles[blockIdx.y];
  int e = tv >> 16, pt = tv & 0xffff;
  int seg0 = offsets[e], cnt = offsets[e + 1] - seg0;
  int n0 = blockIdx.x * BN;

  __shared__ bf16 As[BM * BK];
  __shared__ bf16 Bg[BN * BK];
  __shared__ bf16 Bu[BN * BK];

  int tid = threadIdx.x, lane = tid & 63, wid = tid >> 6;
  int wm = wid >> 1, wn = wid & 1, l15 = lane & 15, l16 = lane >> 4;

  int srow1 = tid >> 2, srow2 = 64 + srow1;
  int kc = (tid & 3) * 8;
  int p1 = pt * BM + srow1, p2 = pt * BM + srow2;
  const bf16* a1 = xb + (size_t)(perm[seg0 + (p1 < cnt ? p1 : 0)] >> 1) * H_DIM + kc;
  const bf16* a2 = xb + (size_t)(perm[seg0 + (p2 < cnt ? p2 : 0)] >> 1) * H_DIM + kc;
  const bf16* g1 = WgT + ((size_t)e * I_DIM + n0 + srow1) * H_DIM + kc;
  const bf16* g2 = WgT + ((size_t)e * I_DIM + n0 + srow2) * H_DIM + kc;
  const bf16* u1 = WuT + ((size_t)e * I_DIM + n0 + srow1) * H_DIM + kc;
  const bf16* u2 = WuT + ((size_t)e * I_DIM + n0 + srow2) * H_DIM + kc;
  bf16* lA1 = &As[tid * 8];       bf16* lA2 = &As[2048 + tid * 8];
  bf16* lG1 = &Bg[tid * 8];       bf16* lG2 = &Bg[2048 + tid * 8];
  bf16* lU1 = &Bu[tid * 8];       bf16* lU2 = &Bu[2048 + tid * 8];

  f32x4 accg[4][4], accu[4][4];
#pragma unroll
  for (int m = 0; m < 4; ++m)
#pragma unroll
    for (int n = 0; n < 4; ++n) {
      accg[m][n] = (f32x4){0.f, 0.f, 0.f, 0.f};
      accu[m][n] = (f32x4){0.f, 0.f, 0.f, 0.f};
    }

  for (int k0 = 0; k0 < H_DIM; k0 += BK) {
    GL16(a1 + k0, lA1);  GL16(a2 + k0, lA2);
    GL16(g1 + k0, lG1);  GL16(g2 + k0, lG2);
    GL16(u1 + k0, lU1);  GL16(u2 + k0, lU2);
    __syncthreads();                 // drains vmcnt -> LDS tiles ready

    bf16x8 af[4], bg[4], bu[4];
#pragma unroll
    for (int m = 0; m < 4; ++m)
      af[m] = *reinterpret_cast<const bf16x8*>(&As[(wm * 64 + m * 16 + l15) * BK + l16 * 8]);
#pragma unroll
    for (int n = 0; n < 4; ++n) {
      bg[n] = *reinterpret_cast<const bf16x8*>(&Bg[(wn * 64 + n * 16 + l15) * BK + l16 * 8]);
      bu[n] = *reinterpret_cast<const bf16x8*>(&Bu[(wn * 64 + n * 16 + l15) * BK + l16 * 8]);
    }
#pragma unroll
    for (int m = 0; m < 4; ++m)
#pragma unroll
      for (int n = 0; n < 4; ++n) {
        accg[m][n] = __builtin_amdgcn_mfma_f32_16x16x32_bf16(af[m], bg[n], accg[m][n], 0, 0, 0);
        accu[m][n] = __builtin_amdgcn_mfma_f32_16x16x32_bf16(af[m], bu[n], accu[m][n], 0, 0, 0);
      }
    __syncthreads();
  }

#pragma unroll
  for (int m = 0; m < 4; ++m) {
#pragma unroll
    for (int r = 0; r < 4; ++r) {
      int p_glob = pt * BM + wm * 64 + m * 16 + l16 * 4 + r;
      if (p_glob < cnt) {
        bf16* hrow = hidden + (size_t)(seg0 + p_glob) * I_DIM;
#pragma unroll
        for (int n = 0; n < 4; ++n) {
          int col = n0 + wn * 64 + n * 16 + l15;
          float g = accg[m][n][r];
          float u = accu[m][n][r];
          float h = g / (1.f + __expf(-g)) * u;
          hrow[col] = (bf16)h;
        }
      }
    }
  }
}

// ------- down grouped GEMM: 64x128 tiles (4x the blocks, 1 GL16 for A, 2 for B) -------
// acc = 2x4 f32x4 = 32 regs -> ~90 VGPR total, no spill at (256,3).
__global__ __launch_bounds__(256, 3) void k_down(const bf16* __restrict__ hidden,
                                                 const bf16* __restrict__ WdT,
                                                 const int* __restrict__ perm,
                                                 const int* __restrict__ offsets,
                                                 const int* __restrict__ tiles64,
                                                 const int* __restrict__ n_tiles,
                                                 float* __restrict__ pair_out) {
  if ((int)blockIdx.y >= n_tiles[1]) return;
  int tv = tiles64[blockIdx.y];
  int e = tv >> 16, pt = tv & 0xffff;
  int seg0 = offsets[e], cnt = offsets[e + 1] - seg0;
  int n0 = blockIdx.x * BN;

  __shared__ bf16 As[64 * BK];       // 4 KB
  __shared__ bf16 Bs[BN * BK];       // 8 KB

  int tid = threadIdx.x, lane = tid & 63, wid = tid >> 6;
  int wm = wid >> 1, wn = wid & 1, l15 = lane & 15, l16 = lane >> 4;

  int srow1 = tid >> 2, srow2 = 64 + srow1;
  int kc = (tid & 3) * 8;
  int pa = pt * 64 + srow1;                       // A: 64 token rows
  const bf16* a1 = hidden + (size_t)(seg0 + (pa < cnt ? pa : 0)) * I_DIM + kc;
  const bf16* b1 = WdT + ((size_t)e * H_DIM + n0 + srow1) * I_DIM + kc;
  const bf16* b2 = WdT + ((size_t)e * H_DIM + n0 + srow2) * I_DIM + kc;
  bf16* lA1 = &As[tid * 8];
  bf16* lB1 = &Bs[tid * 8];  bf16* lB2 = &Bs[2048 + tid * 8];

  f32x4 acc[2][4];
#pragma unroll
  for (int m = 0; m < 2; ++m)
#pragma unroll
    for (int n = 0; n < 4; ++n) acc[m][n] = (f32x4){0.f, 0.f, 0.f, 0.f};

  for (int k0 = 0; k0 < I_DIM; k0 += BK) {
    GL16(a1 + k0, lA1);
    GL16(b1 + k0, lB1);  GL16(b2 + k0, lB2);
    __syncthreads();

    bf16x8 af[2], bfr[4];
#pragma unroll
    for (int m = 0; m < 2; ++m)
      af[m] = *reinterpret_cast<const bf16x8*>(&As[(wm * 32 + m * 16 + l15) * BK + l16 * 8]);
#pragma unroll
    for (int n = 0; n < 4; ++n)
      bfr[n] = *reinterpret_cast<const bf16x8*>(&Bs[(wn * 64 + n * 16 + l15) * BK + l16 * 8]);
#pragma unroll
    for (int m = 0; m < 2; ++m)
#pragma unroll
      for (int n = 0; n < 4; ++n)
        acc[m][n] = __builtin_amdgcn_mfma_f32_16x16x32_bf16(af[m], bfr[n], acc[m][n], 0, 0, 0);
    __syncthreads();
  }

#pragma unroll
  for (int m = 0; m < 2; ++m) {
#pragma unroll
    for (int r = 0; r < 4; ++r) {
      int p_glob = pt * 64 + wm * 32 + m * 16 + l16 * 4 + r;
      if (p_glob < cnt) {
        int pair = perm[seg0 + p_glob];
        float* orow = pair_out + (size_t)pair * H_DIM;
#pragma unroll
        for (int n = 0; n < 4; ++n) {
          int col = n0 + wn * 64 + n * 16 + l15;
          orow[col] = acc[m][n][r];
        }
      }
    }
  }
}

// ---------------- combine ----------------
__global__ __launch_bounds__(256) void k_combine(const float* __restrict__ pair_out,
                                                 const float* __restrict__ rw,
                                                 float* __restrict__ out) {
  int t = blockIdx.x;
  int c = threadIdx.x;
  float w0 = rw[2 * t];
  float w1 = rw[2 * t + 1];
  float4 a = *reinterpret_cast<const float4*>(pair_out + ((size_t)(2 * t)) * H_DIM + c * 4);
  float4 b = *reinterpret_cast<const float4*>(pair_out + ((size_t)(2 * t + 1)) * H_DIM + c * 4);
  float4 o;
  o.x = w0 * a.x + w1 * b.x;
  o.y = w0 * a.y + w1 * b.y;
  o.z = w0 * a.z + w1 * b.z;
  o.w = w0 * a.w + w1 * b.w;
  *reinterpret_cast<float4*>(out + (size_t)t * H_DIM + c * 4) = o;
}

extern "C" void kernel_launch(void* const* d_in, const int* in_sizes, int n_in,
                              void* d_out, int out_size, void* d_ws, size_t ws_size,
                              hipStream_t stream) {
  const float* x  = (const float*)d_in[0];
  const float* Wr = (const float*)d_in[1];
  const float* Wg = (const float*)d_in[2];
  const float* Wu = (const float*)d_in[3];
  const float* Wd = (const float*)d_in[4];
  float* out = (float*)d_out;

  char* ws = (char*)d_ws;
  int*   counts  = (int*)(ws);
  int*   cursor  = (int*)(ws + 256);
  int*   offsets = (int*)(ws + 512);
  int*   n_tiles = (int*)(ws + 768);          // [0]=BM128 count, [1]=BM64 count
  int*   tiles   = (int*)(ws + 1024);
  int*   tiles64 = (int*)(ws + 8192);
  int*   ridx    = (int*)(ws + 64 * 1024);
  float* rw      = (float*)(ws + 128 * 1024);
  int*   perm    = (int*)(ws + 192 * 1024);
  bf16*  xb      = (bf16*)(ws + (1ull << 20));
  bf16*  WgT     = (bf16*)(ws + (16ull << 20));
  bf16*  WuT     = (bf16*)(ws + (66ull << 20));
  bf16*  WdT     = (bf16*)(ws + (116ull << 20));
  bf16*  hidden  = (bf16*)(ws + (166ull << 20));
  float* pair_out = (float*)(ws + (212ull << 20));

  hipMemsetAsync(counts, 0, 64, stream);
  k_xcast<<<dim3(T_TOK * H_DIM / 2048), dim3(256), 0, stream>>>(x, xb);
  k_transpose<<<dim3(I_DIM / 64, H_DIM / 64, E_NUM), dim3(256), 0, stream>>>(Wg, WgT, H_DIM, I_DIM);
  k_transpose<<<dim3(I_DIM / 64, H_DIM / 64, E_NUM), dim3(256), 0, stream>>>(Wu, WuT, H_DIM, I_DIM);
  k_transpose<<<dim3(H_DIM / 64, I_DIM / 64, E_NUM), dim3(256), 0, stream>>>(Wd, WdT, I_DIM, H_DIM);
  k_router<<<dim3(T_TOK / 4), dim3(256), 0, stream>>>(x, Wr, ridx, rw, counts);
  k_scan<<<dim3(1), dim3(64), 0, stream>>>(counts, offsets, cursor, tiles, tiles64, n_tiles);
  k_scatter<<<dim3((T_TOK + 255) / 256), dim3(256), 0, stream>>>(ridx, offsets, cursor, perm);
  k_gateup<<<dim3(I_DIM / BN, MAXTILE), dim3(256), 0, stream>>>(
      xb, WgT, WuT, perm, offsets, tiles, n_tiles, hidden);
  k_down<<<dim3(H_DIM / BN, MAXT64), dim3(256), 0, stream>>>(
      hidden, WdT, perm, offsets, tiles64, n_tiles, pair_out);
  k_combine<<<dim3(T_TOK), dim3(256), 0, stream>>>(pair_out, rw, out);
}

// Round 11
// 474.016 us; speedup vs baseline: 2.8771x; 1.0769x over previous
//
#include <hip/hip_runtime.h>
#include <cstdint>
#include <cstddef>

#define T_TOK 4096
#define H_DIM 1024
#define I_DIM 2816
#define E_NUM 9
#define MAXTILE 76

typedef __bf16 bf16;
typedef bf16 bf16x4 __attribute__((ext_vector_type(4)));
typedef bf16 bf16x8 __attribute__((ext_vector_type(8)));
typedef float f32x4 __attribute__((ext_vector_type(4)));

constexpr int BM = 128, BN = 128, BK = 32;
constexpr int HTILE = BM * BK;          // 4096 elems = 8KB per half

// async global->LDS, 16B per lane; LDS dest must be linear (wave-uniform base + lane*16)
#define GL16(gp, lp)                                                                   \
  __builtin_amdgcn_global_load_lds((const __attribute__((address_space(1))) void*)(gp), \
                                   (__attribute__((address_space(3))) void*)(lp), 16, 0, 0)

// ---------------- x: fp32 -> bf16 ----------------
__global__ __launch_bounds__(256) void k_xcast(const float* __restrict__ x, bf16* __restrict__ xb) {
  size_t i = ((size_t)blockIdx.x * 256 + threadIdx.x) * 8;
  float4 a = *reinterpret_cast<const float4*>(x + i);
  float4 b = *reinterpret_cast<const float4*>(x + i + 4);
  bf16x8 v;
  v[0]=(bf16)a.x; v[1]=(bf16)a.y; v[2]=(bf16)a.z; v[3]=(bf16)a.w;
  v[4]=(bf16)b.x; v[5]=(bf16)b.y; v[6]=(bf16)b.z; v[7]=(bf16)b.w;
  *reinterpret_cast<bf16x8*>(xb + i) = v;
}

// ------- per-expert transpose+convert: in [R][C] fp32 -> out [C][R] bf16 -------
// LDS pad 68 (was 72): read-phase bank conflict 8-way -> 4-way; writes stay aligned+clean.
__global__ __launch_bounds__(256) void k_transpose(const float* __restrict__ in,
                                                   bf16* __restrict__ out, int R, int C) {
  const float* src = in + (size_t)blockIdx.z * R * C;
  bf16* dst = out + (size_t)blockIdx.z * R * C;
  __shared__ bf16 tile[64][68];
  int r0 = blockIdx.y * 64, c0 = blockIdx.x * 64;
  int t = threadIdx.x;
  int tr = t >> 4, tc = (t & 15) * 4;
#pragma unroll
  for (int it = 0; it < 4; ++it) {
    int r = tr + it * 16;
    float4 v = *reinterpret_cast<const float4*>(src + (size_t)(r0 + r) * C + c0 + tc);
    bf16x4 w; w[0]=(bf16)v.x; w[1]=(bf16)v.y; w[2]=(bf16)v.z; w[3]=(bf16)v.w;
    *reinterpret_cast<bf16x4*>(&tile[r][tc]) = w;
  }
  __syncthreads();
#pragma unroll
  for (int it = 0; it < 4; ++it) {
    int oc = tr + it * 16;
    bf16x4 w;
    w[0] = tile[tc + 0][oc]; w[1] = tile[tc + 1][oc];
    w[2] = tile[tc + 2][oc]; w[3] = tile[tc + 3][oc];
    *reinterpret_cast<bf16x4*>(dst + (size_t)(c0 + oc) * R + r0 + tc) = w;
  }
}

// ---------------- router: fp32 logits, softmax top-2, renormalized ----------------
__global__ __launch_bounds__(256) void k_router(const float* __restrict__ x,
                                                const float* __restrict__ Wr,
                                                int* __restrict__ ridx,
                                                float* __restrict__ rw,
                                                int* __restrict__ counts) {
  int lane = threadIdx.x & 63;
  int wid  = threadIdx.x >> 6;
  int t = blockIdx.x * 4 + wid;
  const float* xr = x + (size_t)t * H_DIM;
  float acc[E_NUM];
#pragma unroll
  for (int e = 0; e < E_NUM; ++e) acc[e] = 0.f;
  for (int h = lane; h < H_DIM; h += 64) {
    float xv = xr[h];
    const float* wr = Wr + h * E_NUM;
#pragma unroll
    for (int e = 0; e < E_NUM; ++e) acc[e] += xv * wr[e];
  }
#pragma unroll
  for (int off = 32; off > 0; off >>= 1) {
#pragma unroll
    for (int e = 0; e < E_NUM; ++e) acc[e] += __shfl_xor(acc[e], off);
  }
  if (lane == 0) {
    int i0 = 0;
#pragma unroll
    for (int e = 1; e < E_NUM; ++e) if (acc[e] > acc[i0]) i0 = e;
    int i1 = (i0 == 0) ? 1 : 0;
#pragma unroll
    for (int e = 0; e < E_NUM; ++e) if (e != i0 && acc[e] > acc[i1]) i1 = e;
    float r  = expf(acc[i1] - acc[i0]);
    float w0 = 1.f / (1.f + r);
    float w1 = r / (1.f + r);
    ridx[2 * t]     = i0;
    ridx[2 * t + 1] = i1;
    rw[2 * t]     = w0;
    rw[2 * t + 1] = w1;
    atomicAdd(&counts[i0], 1);
    atomicAdd(&counts[i1], 1);
  }
}

// ------- scan: counts -> offsets, compact tile list, zero cursors -------
__global__ void k_scan(const int* __restrict__ counts, int* __restrict__ offsets,
                       int* __restrict__ cursor, int* __restrict__ tiles,
                       int* __restrict__ n_tiles) {
  if (threadIdx.x == 0) {
    int s = 0, nt = 0;
    for (int e = 0; e < E_NUM; ++e) {
      offsets[e] = s;
      int c = counts[e];
      for (int pt = 0; pt * BM < c && nt < MAXTILE; ++pt) tiles[nt++] = (e << 16) | pt;
      s += c;
    }
    offsets[E_NUM] = s;
    *n_tiles = nt;
  }
  if (threadIdx.x < E_NUM) cursor[threadIdx.x] = 0;
}

// ---------------- scatter pair ids into expert-sorted perm ----------------
__global__ __launch_bounds__(256) void k_scatter(const int* __restrict__ ridx,
                                                 const int* __restrict__ offsets,
                                                 int* __restrict__ cursor,
                                                 int* __restrict__ perm) {
  int t = blockIdx.x * 256 + threadIdx.x;
  if (t >= T_TOK) return;
#pragma unroll
  for (int k = 0; k < 2; ++k) {
    int e = ridx[2 * t + k];
    int pos = atomicAdd(&cursor[e], 1);
    perm[offsets[e] + pos] = 2 * t + k;
  }
}

// ------- fused gate+up grouped GEMM: 2x BK=32 half-tiles per barrier pair -------
// Same 2-barrier-per-iteration structure as the proven 163us kernel; each iteration
// now stages 64 k (12 GL16) and runs 64 MFMAs, halving barrier/drain count (32->16).
__global__ __launch_bounds__(256, 2) void k_gateup(const bf16* __restrict__ xb,
                                                   const bf16* __restrict__ WgT,
                                                   const bf16* __restrict__ WuT,
                                                   const int* __restrict__ perm,
                                                   const int* __restrict__ offsets,
                                                   const int* __restrict__ tiles,
                                                   const int* __restrict__ n_tiles,
                                                   bf16* __restrict__ hidden) {
  if ((int)blockIdx.y >= *n_tiles) return;
  int tv = tiles[blockIdx.y];
  int e = tv >> 16, pt = tv & 0xffff;
  int seg0 = offsets[e], cnt = offsets[e + 1] - seg0;
  int n0 = blockIdx.x * BN;

  __shared__ bf16 As[2 * HTILE];   // 16KB: halves at 0, HTILE
  __shared__ bf16 Bg[2 * HTILE];
  __shared__ bf16 Bu[2 * HTILE];

  int tid = threadIdx.x, lane = tid & 63, wid = tid >> 6;
  int wm = wid >> 1, wn = wid & 1, l15 = lane & 15, l16 = lane >> 4;

  int srow1 = tid >> 2, srow2 = 64 + srow1;
  int kc = (tid & 3) * 8;
  int p1 = pt * BM + srow1, p2 = pt * BM + srow2;
  const bf16* a1 = xb + (size_t)(perm[seg0 + (p1 < cnt ? p1 : 0)] >> 1) * H_DIM + kc;
  const bf16* a2 = xb + (size_t)(perm[seg0 + (p2 < cnt ? p2 : 0)] >> 1) * H_DIM + kc;
  const bf16* g1 = WgT + ((size_t)e * I_DIM + n0 + srow1) * H_DIM + kc;
  const bf16* g2 = WgT + ((size_t)e * I_DIM + n0 + srow2) * H_DIM + kc;
  const bf16* u1 = WuT + ((size_t)e * I_DIM + n0 + srow1) * H_DIM + kc;
  const bf16* u2 = WuT + ((size_t)e * I_DIM + n0 + srow2) * H_DIM + kc;
  bf16* lA1 = &As[tid * 8];       bf16* lA2 = &As[2048 + tid * 8];
  bf16* lG1 = &Bg[tid * 8];       bf16* lG2 = &Bg[2048 + tid * 8];
  bf16* lU1 = &Bu[tid * 8];       bf16* lU2 = &Bu[2048 + tid * 8];

  f32x4 accg[4][4], accu[4][4];
#pragma unroll
  for (int m = 0; m < 4; ++m)
#pragma unroll
    for (int n = 0; n < 4; ++n) {
      accg[m][n] = (f32x4){0.f, 0.f, 0.f, 0.f};
      accu[m][n] = (f32x4){0.f, 0.f, 0.f, 0.f};
    }

  for (int k0 = 0; k0 < H_DIM; k0 += 2 * BK) {
    GL16(a1 + k0, lA1);            GL16(a2 + k0, lA2);
    GL16(a1 + k0 + BK, lA1 + HTILE); GL16(a2 + k0 + BK, lA2 + HTILE);
    GL16(g1 + k0, lG1);            GL16(g2 + k0, lG2);
    GL16(g1 + k0 + BK, lG1 + HTILE); GL16(g2 + k0 + BK, lG2 + HTILE);
    GL16(u1 + k0, lU1);            GL16(u2 + k0, lU2);
    GL16(u1 + k0 + BK, lU1 + HTILE); GL16(u2 + k0 + BK, lU2 + HTILE);
    __syncthreads();               // drains vmcnt -> both halves ready

#pragma unroll
    for (int kk = 0; kk < 2; ++kk) {
      const bf16* Ab = &As[kk * HTILE];
      const bf16* Gb = &Bg[kk * HTILE];
      const bf16* Ub = &Bu[kk * HTILE];
      bf16x8 af[4], bg[4], bu[4];
#pragma unroll
      for (int m = 0; m < 4; ++m)
        af[m] = *reinterpret_cast<const bf16x8*>(&Ab[(wm * 64 + m * 16 + l15) * BK + l16 * 8]);
#pragma unroll
      for (int n = 0; n < 4; ++n) {
        bg[n] = *reinterpret_cast<const bf16x8*>(&Gb[(wn * 64 + n * 16 + l15) * BK + l16 * 8]);
        bu[n] = *reinterpret_cast<const bf16x8*>(&Ub[(wn * 64 + n * 16 + l15) * BK + l16 * 8]);
      }
#pragma unroll
      for (int m = 0; m < 4; ++m)
#pragma unroll
        for (int n = 0; n < 4; ++n) {
          accg[m][n] = __builtin_amdgcn_mfma_f32_16x16x32_bf16(af[m], bg[n], accg[m][n], 0, 0, 0);
          accu[m][n] = __builtin_amdgcn_mfma_f32_16x16x32_bf16(af[m], bu[n], accu[m][n], 0, 0, 0);
        }
    }
    __syncthreads();
  }

#pragma unroll
  for (int m = 0; m < 4; ++m) {
#pragma unroll
    for (int r = 0; r < 4; ++r) {
      int p_glob = pt * BM + wm * 64 + m * 16 + l16 * 4 + r;
      if (p_glob < cnt) {
        bf16* hrow = hidden + (size_t)(seg0 + p_glob) * I_DIM;
#pragma unroll
        for (int n = 0; n < 4; ++n) {
          int col = n0 + wn * 64 + n * 16 + l15;
          float g = accg[m][n][r];
          float u = accu[m][n][r];
          float h = g / (1.f + __expf(-g)) * u;
          hrow[col] = (bf16)h;
        }
      }
    }
  }
}

// ------- down grouped GEMM: 128x128, 2x BK=32 half-tiles per barrier pair (88->44) -------
__global__ __launch_bounds__(256, 2) void k_down(const bf16* __restrict__ hidden,
                                                 const bf16* __restrict__ WdT,
                                                 const int* __restrict__ perm,
                                                 const int* __restrict__ offsets,
                                                 const int* __restrict__ tiles,
                                                 const int* __restrict__ n_tiles,
                                                 float* __restrict__ pair_out) {
  if ((int)blockIdx.y >= *n_tiles) return;
  int tv = tiles[blockIdx.y];
  int e = tv >> 16, pt = tv & 0xffff;
  int seg0 = offsets[e], cnt = offsets[e + 1] - seg0;
  int n0 = blockIdx.x * BN;

  __shared__ bf16 As[2 * HTILE];
  __shared__ bf16 Bs[2 * HTILE];

  int tid = threadIdx.x, lane = tid & 63, wid = tid >> 6;
  int wm = wid >> 1, wn = wid & 1, l15 = lane & 15, l16 = lane >> 4;

  int srow1 = tid >> 2, srow2 = 64 + srow1;
  int kc = (tid & 3) * 8;
  int p1 = pt * BM + srow1, p2 = pt * BM + srow2;
  const bf16* a1 = hidden + (size_t)(seg0 + (p1 < cnt ? p1 : 0)) * I_DIM + kc;
  const bf16* a2 = hidden + (size_t)(seg0 + (p2 < cnt ? p2 : 0)) * I_DIM + kc;
  const bf16* b1 = WdT + ((size_t)e * H_DIM + n0 + srow1) * I_DIM + kc;
  const bf16* b2 = WdT + ((size_t)e * H_DIM + n0 + srow2) * I_DIM + kc;
  bf16* lA1 = &As[tid * 8];  bf16* lA2 = &As[2048 + tid * 8];
  bf16* lB1 = &Bs[tid * 8];  bf16* lB2 = &Bs[2048 + tid * 8];

  f32x4 acc[4][4];
#pragma unroll
  for (int m = 0; m < 4; ++m)
#pragma unroll
    for (int n = 0; n < 4; ++n) acc[m][n] = (f32x4){0.f, 0.f, 0.f, 0.f};

  for (int k0 = 0; k0 < I_DIM; k0 += 2 * BK) {
    GL16(a1 + k0, lA1);            GL16(a2 + k0, lA2);
    GL16(a1 + k0 + BK, lA1 + HTILE); GL16(a2 + k0 + BK, lA2 + HTILE);
    GL16(b1 + k0, lB1);            GL16(b2 + k0, lB2);
    GL16(b1 + k0 + BK, lB1 + HTILE); GL16(b2 + k0 + BK, lB2 + HTILE);
    __syncthreads();

#pragma unroll
    for (int kk = 0; kk < 2; ++kk) {
      const bf16* Ab = &As[kk * HTILE];
      const bf16* Bb = &Bs[kk * HTILE];
      bf16x8 af[4], bfr[4];
#pragma unroll
      for (int m = 0; m < 4; ++m)
        af[m] = *reinterpret_cast<const bf16x8*>(&Ab[(wm * 64 + m * 16 + l15) * BK + l16 * 8]);
#pragma unroll
      for (int n = 0; n < 4; ++n)
        bfr[n] = *reinterpret_cast<const bf16x8*>(&Bb[(wn * 64 + n * 16 + l15) * BK + l16 * 8]);
#pragma unroll
      for (int m = 0; m < 4; ++m)
#pragma unroll
        for (int n = 0; n < 4; ++n)
          acc[m][n] = __builtin_amdgcn_mfma_f32_16x16x32_bf16(af[m], bfr[n], acc[m][n], 0, 0, 0);
    }
    __syncthreads();
  }

#pragma unroll
  for (int m = 0; m < 4; ++m) {
#pragma unroll
    for (int r = 0; r < 4; ++r) {
      int p_glob = pt * BM + wm * 64 + m * 16 + l16 * 4 + r;
      if (p_glob < cnt) {
        int pair = perm[seg0 + p_glob];
        float* orow = pair_out + (size_t)pair * H_DIM;
#pragma unroll
        for (int n = 0; n < 4; ++n) {
          int col = n0 + wn * 64 + n * 16 + l15;
          orow[col] = acc[m][n][r];
        }
      }
    }
  }
}

// ---------------- combine ----------------
__global__ __launch_bounds__(256) void k_combine(const float* __restrict__ pair_out,
                                                 const float* __restrict__ rw,
                                                 float* __restrict__ out) {
  int t = blockIdx.x;
  int c = threadIdx.x;
  float w0 = rw[2 * t];
  float w1 = rw[2 * t + 1];
  float4 a = *reinterpret_cast<const float4*>(pair_out + ((size_t)(2 * t)) * H_DIM + c * 4);
  float4 b = *reinterpret_cast<const float4*>(pair_out + ((size_t)(2 * t + 1)) * H_DIM + c * 4);
  float4 o;
  o.x = w0 * a.x + w1 * b.x;
  o.y = w0 * a.y + w1 * b.y;
  o.z = w0 * a.z + w1 * b.z;
  o.w = w0 * a.w + w1 * b.w;
  *reinterpret_cast<float4*>(out + (size_t)t * H_DIM + c * 4) = o;
}

extern "C" void kernel_launch(void* const* d_in, const int* in_sizes, int n_in,
                              void* d_out, int out_size, void* d_ws, size_t ws_size,
                              hipStream_t stream) {
  const float* x  = (const float*)d_in[0];
  const float* Wr = (const float*)d_in[1];
  const float* Wg = (const float*)d_in[2];
  const float* Wu = (const float*)d_in[3];
  const float* Wd = (const float*)d_in[4];
  float* out = (float*)d_out;

  char* ws = (char*)d_ws;
  int*   counts  = (int*)(ws);
  int*   cursor  = (int*)(ws + 256);
  int*   offsets = (int*)(ws + 512);
  int*   n_tiles = (int*)(ws + 768);
  int*   tiles   = (int*)(ws + 1024);
  int*   ridx    = (int*)(ws + 64 * 1024);
  float* rw      = (float*)(ws + 128 * 1024);
  int*   perm    = (int*)(ws + 192 * 1024);
  bf16*  xb      = (bf16*)(ws + (1ull << 20));
  bf16*  WgT     = (bf16*)(ws + (16ull << 20));
  bf16*  WuT     = (bf16*)(ws + (66ull << 20));
  bf16*  WdT     = (bf16*)(ws + (116ull << 20));
  bf16*  hidden  = (bf16*)(ws + (166ull << 20));
  float* pair_out = (float*)(ws + (212ull << 20));

  hipMemsetAsync(counts, 0, 64, stream);
  k_xcast<<<dim3(T_TOK * H_DIM / 2048), dim3(256), 0, stream>>>(x, xb);
  k_transpose<<<dim3(I_DIM / 64, H_DIM / 64, E_NUM), dim3(256), 0, stream>>>(Wg, WgT, H_DIM, I_DIM);
  k_transpose<<<dim3(I_DIM / 64, H_DIM / 64, E_NUM), dim3(256), 0, stream>>>(Wu, WuT, H_DIM, I_DIM);
  k_transpose<<<dim3(H_DIM / 64, I_DIM / 64, E_NUM), dim3(256), 0, stream>>>(Wd, WdT, I_DIM, H_DIM);
  k_router<<<dim3(T_TOK / 4), dim3(256), 0, stream>>>(x, Wr, ridx, rw, counts);
  k_scan<<<dim3(1), dim3(64), 0, stream>>>(counts, offsets, cursor, tiles, n_tiles);
  k_scatter<<<dim3((T_TOK + 255) / 256), dim3(256), 0, stream>>>(ridx, offsets, cursor, perm);
  k_gateup<<<dim3(I_DIM / BN, MAXTILE), dim3(256), 0, stream>>>(
      xb, WgT, WuT, perm, offsets, tiles, n_tiles, hidden);
  k_down<<<dim3(H_DIM / BN, MAXTILE), dim3(256), 0, stream>>>(
      hidden, WdT, perm, offsets, tiles, n_tiles, pair_out);
  k_combine<<<dim3(T_TOK), dim3(256), 0, stream>>>(pair_out, rw, out);
}

// Round 12
// 473.827 us; speedup vs baseline: 2.8783x; 1.0004x over previous
//
#include <hip/hip_runtime.h>
#include <cstdint>
#include <cstddef>

#define T_TOK 4096
#define H_DIM 1024
#define I_DIM 2816
#define E_NUM 9
#define MAXTILE 76
#define NPANEL (I_DIM / 128)          // 22
#define GUGRID (NPANEL * MAXTILE)     // 1672 = 8 * 209, bijective XCD swizzle
#define GUCHUNK (GUGRID / 8)          // 209

typedef __bf16 bf16;
typedef bf16 bf16x4 __attribute__((ext_vector_type(4)));
typedef bf16 bf16x8 __attribute__((ext_vector_type(8)));
typedef float f32x4 __attribute__((ext_vector_type(4)));

constexpr int BM = 128, BN = 128, BK = 32;
constexpr int HTILE = BM * BK;          // 4096 elems = 8KB per half

// async global->LDS, 16B per lane; LDS dest must be linear (wave-uniform base + lane*16)
#define GL16(gp, lp)                                                                   \
  __builtin_amdgcn_global_load_lds((const __attribute__((address_space(1))) void*)(gp), \
                                   (__attribute__((address_space(3))) void*)(lp), 16, 0, 0)

// ---------------- x: fp32 -> bf16 ----------------
__global__ __launch_bounds__(256) void k_xcast(const float* __restrict__ x, bf16* __restrict__ xb) {
  size_t i = ((size_t)blockIdx.x * 256 + threadIdx.x) * 8;
  float4 a = *reinterpret_cast<const float4*>(x + i);
  float4 b = *reinterpret_cast<const float4*>(x + i + 4);
  bf16x8 v;
  v[0]=(bf16)a.x; v[1]=(bf16)a.y; v[2]=(bf16)a.z; v[3]=(bf16)a.w;
  v[4]=(bf16)b.x; v[5]=(bf16)b.y; v[6]=(bf16)b.z; v[7]=(bf16)b.w;
  *reinterpret_cast<bf16x8*>(xb + i) = v;
}

// ------- per-expert transpose+convert: in [R][C] fp32 -> out [C][R] bf16 -------
__global__ __launch_bounds__(256) void k_transpose(const float* __restrict__ in,
                                                   bf16* __restrict__ out, int R, int C) {
  const float* src = in + (size_t)blockIdx.z * R * C;
  bf16* dst = out + (size_t)blockIdx.z * R * C;
  __shared__ bf16 tile[64][68];
  int r0 = blockIdx.y * 64, c0 = blockIdx.x * 64;
  int t = threadIdx.x;
  int tr = t >> 4, tc = (t & 15) * 4;
#pragma unroll
  for (int it = 0; it < 4; ++it) {
    int r = tr + it * 16;
    float4 v = *reinterpret_cast<const float4*>(src + (size_t)(r0 + r) * C + c0 + tc);
    bf16x4 w; w[0]=(bf16)v.x; w[1]=(bf16)v.y; w[2]=(bf16)v.z; w[3]=(bf16)v.w;
    *reinterpret_cast<bf16x4*>(&tile[r][tc]) = w;
  }
  __syncthreads();
#pragma unroll
  for (int it = 0; it < 4; ++it) {
    int oc = tr + it * 16;
    bf16x4 w;
    w[0] = tile[tc + 0][oc]; w[1] = tile[tc + 1][oc];
    w[2] = tile[tc + 2][oc]; w[3] = tile[tc + 3][oc];
    *reinterpret_cast<bf16x4*>(dst + (size_t)(c0 + oc) * R + r0 + tc) = w;
  }
}

// ---------------- router: fp32 logits, softmax top-2, renormalized ----------------
__global__ __launch_bounds__(256) void k_router(const float* __restrict__ x,
                                                const float* __restrict__ Wr,
                                                int* __restrict__ ridx,
                                                float* __restrict__ rw,
                                                int* __restrict__ counts) {
  int lane = threadIdx.x & 63;
  int wid  = threadIdx.x >> 6;
  int t = blockIdx.x * 4 + wid;
  const float* xr = x + (size_t)t * H_DIM;
  float acc[E_NUM];
#pragma unroll
  for (int e = 0; e < E_NUM; ++e) acc[e] = 0.f;
  for (int h = lane; h < H_DIM; h += 64) {
    float xv = xr[h];
    const float* wr = Wr + h * E_NUM;
#pragma unroll
    for (int e = 0; e < E_NUM; ++e) acc[e] += xv * wr[e];
  }
#pragma unroll
  for (int off = 32; off > 0; off >>= 1) {
#pragma unroll
    for (int e = 0; e < E_NUM; ++e) acc[e] += __shfl_xor(acc[e], off);
  }
  if (lane == 0) {
    int i0 = 0;
#pragma unroll
    for (int e = 1; e < E_NUM; ++e) if (acc[e] > acc[i0]) i0 = e;
    int i1 = (i0 == 0) ? 1 : 0;
#pragma unroll
    for (int e = 0; e < E_NUM; ++e) if (e != i0 && acc[e] > acc[i1]) i1 = e;
    float r  = expf(acc[i1] - acc[i0]);
    float w0 = 1.f / (1.f + r);
    float w1 = r / (1.f + r);
    ridx[2 * t]     = i0;
    ridx[2 * t + 1] = i1;
    rw[2 * t]     = w0;
    rw[2 * t + 1] = w1;
    atomicAdd(&counts[i0], 1);
    atomicAdd(&counts[i1], 1);
  }
}

// ------- scan: counts -> offsets, compact tile list, zero cursors -------
__global__ void k_scan(const int* __restrict__ counts, int* __restrict__ offsets,
                       int* __restrict__ cursor, int* __restrict__ tiles,
                       int* __restrict__ n_tiles) {
  if (threadIdx.x == 0) {
    int s = 0, nt = 0;
    for (int e = 0; e < E_NUM; ++e) {
      offsets[e] = s;
      int c = counts[e];
      for (int pt = 0; pt * BM < c && nt < MAXTILE; ++pt) tiles[nt++] = (e << 16) | pt;
      s += c;
    }
    offsets[E_NUM] = s;
    *n_tiles = nt;
  }
  if (threadIdx.x < E_NUM) cursor[threadIdx.x] = 0;
}

// ---------------- scatter pair ids into expert-sorted perm ----------------
__global__ __launch_bounds__(256) void k_scatter(const int* __restrict__ ridx,
                                                 const int* __restrict__ offsets,
                                                 int* __restrict__ cursor,
                                                 int* __restrict__ perm) {
  int t = blockIdx.x * 256 + threadIdx.x;
  if (t >= T_TOK) return;
#pragma unroll
  for (int k = 0; k < 2; ++k) {
    int e = ridx[2 * t + k];
    int pos = atomicAdd(&cursor[e], 1);
    perm[offsets[e] + pos] = 2 * t + k;
  }
}

// ------- fused gate+up grouped GEMM: BK=64/barrier-pair + XCD-chunked swizzle (T1) -------
__global__ __launch_bounds__(256, 2) void k_gateup(const bf16* __restrict__ xb,
                                                   const bf16* __restrict__ WgT,
                                                   const bf16* __restrict__ WuT,
                                                   const int* __restrict__ perm,
                                                   const int* __restrict__ offsets,
                                                   const int* __restrict__ tiles,
                                                   const int* __restrict__ n_tiles,
                                                   bf16* __restrict__ hidden) {
  // bijective XCD swizzle: 1672 = 8*209; n0 fast within a 209-chunk -> same tile's
  // panels + consecutive (mostly same-expert) tiles land on one XCD's L2.
  int flat = blockIdx.x;
  int swz = (flat & 7) * GUCHUNK + (flat >> 3);
  int ti = swz / NPANEL;
  int n0 = (swz % NPANEL) * BN;
  if (ti >= *n_tiles) return;
  int tv = tiles[ti];
  int e = tv >> 16, pt = tv & 0xffff;
  int seg0 = offsets[e], cnt = offsets[e + 1] - seg0;

  __shared__ bf16 As[2 * HTILE];   // 16KB: halves at 0, HTILE
  __shared__ bf16 Bg[2 * HTILE];
  __shared__ bf16 Bu[2 * HTILE];

  int tid = threadIdx.x, lane = tid & 63, wid = tid >> 6;
  int wm = wid >> 1, wn = wid & 1, l15 = lane & 15, l16 = lane >> 4;

  int srow1 = tid >> 2, srow2 = 64 + srow1;
  int kc = (tid & 3) * 8;
  int p1 = pt * BM + srow1, p2 = pt * BM + srow2;
  const bf16* a1 = xb + (size_t)(perm[seg0 + (p1 < cnt ? p1 : 0)] >> 1) * H_DIM + kc;
  const bf16* a2 = xb + (size_t)(perm[seg0 + (p2 < cnt ? p2 : 0)] >> 1) * H_DIM + kc;
  const bf16* g1 = WgT + ((size_t)e * I_DIM + n0 + srow1) * H_DIM + kc;
  const bf16* g2 = WgT + ((size_t)e * I_DIM + n0 + srow2) * H_DIM + kc;
  const bf16* u1 = WuT + ((size_t)e * I_DIM + n0 + srow1) * H_DIM + kc;
  const bf16* u2 = WuT + ((size_t)e * I_DIM + n0 + srow2) * H_DIM + kc;
  bf16* lA1 = &As[tid * 8];       bf16* lA2 = &As[2048 + tid * 8];
  bf16* lG1 = &Bg[tid * 8];       bf16* lG2 = &Bg[2048 + tid * 8];
  bf16* lU1 = &Bu[tid * 8];       bf16* lU2 = &Bu[2048 + tid * 8];

  f32x4 accg[4][4], accu[4][4];
#pragma unroll
  for (int m = 0; m < 4; ++m)
#pragma unroll
    for (int n = 0; n < 4; ++n) {
      accg[m][n] = (f32x4){0.f, 0.f, 0.f, 0.f};
      accu[m][n] = (f32x4){0.f, 0.f, 0.f, 0.f};
    }

  for (int k0 = 0; k0 < H_DIM; k0 += 2 * BK) {
    GL16(a1 + k0, lA1);            GL16(a2 + k0, lA2);
    GL16(a1 + k0 + BK, lA1 + HTILE); GL16(a2 + k0 + BK, lA2 + HTILE);
    GL16(g1 + k0, lG1);            GL16(g2 + k0, lG2);
    GL16(g1 + k0 + BK, lG1 + HTILE); GL16(g2 + k0 + BK, lG2 + HTILE);
    GL16(u1 + k0, lU1);            GL16(u2 + k0, lU2);
    GL16(u1 + k0 + BK, lU1 + HTILE); GL16(u2 + k0 + BK, lU2 + HTILE);
    __syncthreads();               // drains vmcnt -> both halves ready

#pragma unroll
    for (int kk = 0; kk < 2; ++kk) {
      const bf16* Ab = &As[kk * HTILE];
      const bf16* Gb = &Bg[kk * HTILE];
      const bf16* Ub = &Bu[kk * HTILE];
      bf16x8 af[4], bg[4], bu[4];
#pragma unroll
      for (int m = 0; m < 4; ++m)
        af[m] = *reinterpret_cast<const bf16x8*>(&Ab[(wm * 64 + m * 16 + l15) * BK + l16 * 8]);
#pragma unroll
      for (int n = 0; n < 4; ++n) {
        bg[n] = *reinterpret_cast<const bf16x8*>(&Gb[(wn * 64 + n * 16 + l15) * BK + l16 * 8]);
        bu[n] = *reinterpret_cast<const bf16x8*>(&Ub[(wn * 64 + n * 16 + l15) * BK + l16 * 8]);
      }
#pragma unroll
      for (int m = 0; m < 4; ++m)
#pragma unroll
        for (int n = 0; n < 4; ++n) {
          accg[m][n] = __builtin_amdgcn_mfma_f32_16x16x32_bf16(af[m], bg[n], accg[m][n], 0, 0, 0);
          accu[m][n] = __builtin_amdgcn_mfma_f32_16x16x32_bf16(af[m], bu[n], accu[m][n], 0, 0, 0);
        }
    }
    __syncthreads();
  }

#pragma unroll
  for (int m = 0; m < 4; ++m) {
#pragma unroll
    for (int r = 0; r < 4; ++r) {
      int p_glob = pt * BM + wm * 64 + m * 16 + l16 * 4 + r;
      if (p_glob < cnt) {
        bf16* hrow = hidden + (size_t)(seg0 + p_glob) * I_DIM;
#pragma unroll
        for (int n = 0; n < 4; ++n) {
          int col = n0 + wn * 64 + n * 16 + l15;
          float g = accg[m][n][r];
          float u = accu[m][n][r];
          float h = g / (1.f + __expf(-g)) * u;
          hrow[col] = (bf16)h;
        }
      }
    }
  }
}

// ------- down grouped GEMM: split-K x2 into separate bf16 partial buffers -------
// blockIdx.z in {0,1}: K range [z*1408, z*1408+1408). No atomics, no memset:
// every pair row is written once per z. Combine sums the halves (deterministic).
__global__ __launch_bounds__(256, 2) void k_down(const bf16* __restrict__ hidden,
                                                 const bf16* __restrict__ WdT,
                                                 const int* __restrict__ perm,
                                                 const int* __restrict__ offsets,
                                                 const int* __restrict__ tiles,
                                                 const int* __restrict__ n_tiles,
                                                 bf16* __restrict__ pair_half) {
  if ((int)blockIdx.y >= *n_tiles) return;
  int tv = tiles[blockIdx.y];
  int e = tv >> 16, pt = tv & 0xffff;
  int seg0 = offsets[e], cnt = offsets[e + 1] - seg0;
  int n0 = blockIdx.x * BN;
  int kz = blockIdx.z * (I_DIM / 2);
  bf16* pout = pair_half + (size_t)blockIdx.z * 2 * T_TOK * H_DIM;

  __shared__ bf16 As[2 * HTILE];
  __shared__ bf16 Bs[2 * HTILE];

  int tid = threadIdx.x, lane = tid & 63, wid = tid >> 6;
  int wm = wid >> 1, wn = wid & 1, l15 = lane & 15, l16 = lane >> 4;

  int srow1 = tid >> 2, srow2 = 64 + srow1;
  int kc = (tid & 3) * 8;
  int p1 = pt * BM + srow1, p2 = pt * BM + srow2;
  const bf16* a1 = hidden + (size_t)(seg0 + (p1 < cnt ? p1 : 0)) * I_DIM + kz + kc;
  const bf16* a2 = hidden + (size_t)(seg0 + (p2 < cnt ? p2 : 0)) * I_DIM + kz + kc;
  const bf16* b1 = WdT + ((size_t)e * H_DIM + n0 + srow1) * I_DIM + kz + kc;
  const bf16* b2 = WdT + ((size_t)e * H_DIM + n0 + srow2) * I_DIM + kz + kc;
  bf16* lA1 = &As[tid * 8];  bf16* lA2 = &As[2048 + tid * 8];
  bf16* lB1 = &Bs[tid * 8];  bf16* lB2 = &Bs[2048 + tid * 8];

  f32x4 acc[4][4];
#pragma unroll
  for (int m = 0; m < 4; ++m)
#pragma unroll
    for (int n = 0; n < 4; ++n) acc[m][n] = (f32x4){0.f, 0.f, 0.f, 0.f};

  for (int k0 = 0; k0 < I_DIM / 2; k0 += 2 * BK) {
    GL16(a1 + k0, lA1);            GL16(a2 + k0, lA2);
    GL16(a1 + k0 + BK, lA1 + HTILE); GL16(a2 + k0 + BK, lA2 + HTILE);
    GL16(b1 + k0, lB1);            GL16(b2 + k0, lB2);
    GL16(b1 + k0 + BK, lB1 + HTILE); GL16(b2 + k0 + BK, lB2 + HTILE);
    __syncthreads();

#pragma unroll
    for (int kk = 0; kk < 2; ++kk) {
      const bf16* Ab = &As[kk * HTILE];
      const bf16* Bb = &Bs[kk * HTILE];
      bf16x8 af[4], bfr[4];
#pragma unroll
      for (int m = 0; m < 4; ++m)
        af[m] = *reinterpret_cast<const bf16x8*>(&Ab[(wm * 64 + m * 16 + l15) * BK + l16 * 8]);
#pragma unroll
      for (int n = 0; n < 4; ++n)
        bfr[n] = *reinterpret_cast<const bf16x8*>(&Bb[(wn * 64 + n * 16 + l15) * BK + l16 * 8]);
#pragma unroll
      for (int m = 0; m < 4; ++m)
#pragma unroll
        for (int n = 0; n < 4; ++n)
          acc[m][n] = __builtin_amdgcn_mfma_f32_16x16x32_bf16(af[m], bfr[n], acc[m][n], 0, 0, 0);
    }
    __syncthreads();
  }

#pragma unroll
  for (int m = 0; m < 4; ++m) {
#pragma unroll
    for (int r = 0; r < 4; ++r) {
      int p_glob = pt * BM + wm * 64 + m * 16 + l16 * 4 + r;
      if (p_glob < cnt) {
        int pair = perm[seg0 + p_glob];
        bf16* orow = pout + (size_t)pair * H_DIM;
#pragma unroll
        for (int n = 0; n < 4; ++n) {
          int col = n0 + wn * 64 + n * 16 + l15;
          orow[col] = (bf16)acc[m][n][r];
        }
      }
    }
  }
}

// ------- combine: out[t] = w0*(z0[2t]+z1[2t]) + w1*(z0[2t+1]+z1[2t+1]) -------
__global__ __launch_bounds__(256) void k_combine(const bf16* __restrict__ pair_half,
                                                 const float* __restrict__ rw,
                                                 float* __restrict__ out) {
  int t = blockIdx.x;
  int c = threadIdx.x;                        // 256 threads * 4 = 1024
  const bf16* z0 = pair_half;
  const bf16* z1 = pair_half + (size_t)2 * T_TOK * H_DIM;
  float w0 = rw[2 * t];
  float w1 = rw[2 * t + 1];
  size_t r0 = (size_t)(2 * t) * H_DIM + c * 4;
  size_t r1 = (size_t)(2 * t + 1) * H_DIM + c * 4;
  bf16x4 a0 = *reinterpret_cast<const bf16x4*>(z0 + r0);
  bf16x4 a1 = *reinterpret_cast<const bf16x4*>(z1 + r0);
  bf16x4 b0 = *reinterpret_cast<const bf16x4*>(z0 + r1);
  bf16x4 b1 = *reinterpret_cast<const bf16x4*>(z1 + r1);
  float4 o;
  o.x = w0 * ((float)a0[0] + (float)a1[0]) + w1 * ((float)b0[0] + (float)b1[0]);
  o.y = w0 * ((float)a0[1] + (float)a1[1]) + w1 * ((float)b0[1] + (float)b1[1]);
  o.z = w0 * ((float)a0[2] + (float)a1[2]) + w1 * ((float)b0[2] + (float)b1[2]);
  o.w = w0 * ((float)a0[3] + (float)a1[3]) + w1 * ((float)b0[3] + (float)b1[3]);
  *reinterpret_cast<float4*>(out + (size_t)t * H_DIM + c * 4) = o;
}

extern "C" void kernel_launch(void* const* d_in, const int* in_sizes, int n_in,
                              void* d_out, int out_size, void* d_ws, size_t ws_size,
                              hipStream_t stream) {
  const float* x  = (const float*)d_in[0];
  const float* Wr = (const float*)d_in[1];
  const float* Wg = (const float*)d_in[2];
  const float* Wu = (const float*)d_in[3];
  const float* Wd = (const float*)d_in[4];
  float* out = (float*)d_out;

  char* ws = (char*)d_ws;
  int*   counts  = (int*)(ws);
  int*   cursor  = (int*)(ws + 256);
  int*   offsets = (int*)(ws + 512);
  int*   n_tiles = (int*)(ws + 768);
  int*   tiles   = (int*)(ws + 1024);
  int*   ridx    = (int*)(ws + 64 * 1024);
  float* rw      = (float*)(ws + 128 * 1024);
  int*   perm    = (int*)(ws + 192 * 1024);
  bf16*  xb      = (bf16*)(ws + (1ull << 20));
  bf16*  WgT     = (bf16*)(ws + (16ull << 20));
  bf16*  WuT     = (bf16*)(ws + (66ull << 20));
  bf16*  WdT     = (bf16*)(ws + (116ull << 20));
  bf16*  hidden  = (bf16*)(ws + (166ull << 20));
  bf16*  pair_half = (bf16*)(ws + (212ull << 20));   // [2][8192][1024] bf16 = 32 MiB

  hipMemsetAsync(counts, 0, 64, stream);
  k_xcast<<<dim3(T_TOK * H_DIM / 2048), dim3(256), 0, stream>>>(x, xb);
  k_transpose<<<dim3(I_DIM / 64, H_DIM / 64, E_NUM), dim3(256), 0, stream>>>(Wg, WgT, H_DIM, I_DIM);
  k_transpose<<<dim3(I_DIM / 64, H_DIM / 64, E_NUM), dim3(256), 0, stream>>>(Wu, WuT, H_DIM, I_DIM);
  k_transpose<<<dim3(H_DIM / 64, I_DIM / 64, E_NUM), dim3(256), 0, stream>>>(Wd, WdT, I_DIM, H_DIM);
  k_router<<<dim3(T_TOK / 4), dim3(256), 0, stream>>>(x, Wr, ridx, rw, counts);
  k_scan<<<dim3(1), dim3(64), 0, stream>>>(counts, offsets, cursor, tiles, n_tiles);
  k_scatter<<<dim3((T_TOK + 255) / 256), dim3(256), 0, stream>>>(ridx, offsets, cursor, perm);
  k_gateup<<<dim3(GUGRID), dim3(256), 0, stream>>>(
      xb, WgT, WuT, perm, offsets, tiles, n_tiles, hidden);
  k_down<<<dim3(H_DIM / BN, MAXTILE, 2), dim3(256), 0, stream>>>(
      hidden, WdT, perm, offsets, tiles, n_tiles, pair_half);
  k_combine<<<dim3(T_TOK), dim3(256), 0, stream>>>(pair_half, rw, out);
}

// Round 13
// 470.791 us; speedup vs baseline: 2.8968x; 1.0064x over previous
//
#include <hip/hip_runtime.h>
#include <cstdint>
#include <cstddef>

#define T_TOK 4096
#define H_DIM 1024
#define I_DIM 2816
#define E_NUM 9
#define MAXTILE 76

typedef __bf16 bf16;
typedef bf16 bf16x4 __attribute__((ext_vector_type(4)));
typedef bf16 bf16x8 __attribute__((ext_vector_type(8)));
typedef float f32x4 __attribute__((ext_vector_type(4)));

constexpr int BM = 128, BN = 128, BK = 32;
constexpr int HTILE = BM * BK;          // 4096 elems = 8KB per half

// async global->LDS, 16B per lane; LDS dest must be linear (wave-uniform base + lane*16)
#define GL16(gp, lp)                                                                   \
  __builtin_amdgcn_global_load_lds((const __attribute__((address_space(1))) void*)(gp), \
                                   (__attribute__((address_space(3))) void*)(lp), 16, 0, 0)

// ---------------- x: fp32 -> bf16 ----------------
__global__ __launch_bounds__(256) void k_xcast(const float* __restrict__ x, bf16* __restrict__ xb) {
  size_t i = ((size_t)blockIdx.x * 256 + threadIdx.x) * 8;
  float4 a = *reinterpret_cast<const float4*>(x + i);
  float4 b = *reinterpret_cast<const float4*>(x + i + 4);
  bf16x8 v;
  v[0]=(bf16)a.x; v[1]=(bf16)a.y; v[2]=(bf16)a.z; v[3]=(bf16)a.w;
  v[4]=(bf16)b.x; v[5]=(bf16)b.y; v[6]=(bf16)b.z; v[7]=(bf16)b.w;
  *reinterpret_cast<bf16x8*>(xb + i) = v;
}

// ------- transpose+convert core: one 64x64 tile, vectorized 16B writes -------
// write phase: thread -> (oc = t>>2, q = t&3); emits out[c0+oc][r0+q*16 .. +15]
// as 2x bf16x8. LDS row stride 136B: q*16 rows = 544 dwords = 0 mod 32 -> q is
// bank-neutral; oc pairs share a dword (broadcast). ~4-way max on reads.
__device__ __forceinline__ void transpose_tile(const float* __restrict__ src,
                                               bf16* __restrict__ dst, int R, int C) {
  __shared__ bf16 tile[64][68];
  int r0 = blockIdx.y * 64, c0 = blockIdx.x * 64;
  int t = threadIdx.x;
  int tr = t >> 4, tc = (t & 15) * 4;
#pragma unroll
  for (int it = 0; it < 4; ++it) {
    int r = tr + it * 16;
    float4 v = *reinterpret_cast<const float4*>(src + (size_t)(r0 + r) * C + c0 + tc);
    bf16x4 w; w[0]=(bf16)v.x; w[1]=(bf16)v.y; w[2]=(bf16)v.z; w[3]=(bf16)v.w;
    *reinterpret_cast<bf16x4*>(&tile[r][tc]) = w;
  }
  __syncthreads();
  int oc = t >> 2;
  int q  = t & 3;
  bf16x8 w0, w1;
#pragma unroll
  for (int j = 0; j < 8; ++j) w0[j] = tile[q * 16 + j][oc];
#pragma unroll
  for (int j = 0; j < 8; ++j) w1[j] = tile[q * 16 + 8 + j][oc];
  bf16* dp = dst + (size_t)(c0 + oc) * R + r0 + q * 16;
  *reinterpret_cast<bf16x8*>(dp)     = w0;
  *reinterpret_cast<bf16x8*>(dp + 8) = w1;
}

// fused Wg+Wu transpose: z in [0,18): z<9 -> Wg, else Wu. [H][I] -> [I][H]
__global__ __launch_bounds__(256) void k_transpose_gu(const float* __restrict__ Wg,
                                                      const float* __restrict__ Wu,
                                                      bf16* __restrict__ WgT,
                                                      bf16* __restrict__ WuT) {
  int z = blockIdx.z;
  const float* src = (z < 9) ? (Wg + (size_t)z * H_DIM * I_DIM)
                             : (Wu + (size_t)(z - 9) * H_DIM * I_DIM);
  bf16* dst = (z < 9) ? (WgT + (size_t)z * H_DIM * I_DIM)
                      : (WuT + (size_t)(z - 9) * H_DIM * I_DIM);
  transpose_tile(src, dst, H_DIM, I_DIM);
}

// Wd transpose: [I][H] -> [H][I]
__global__ __launch_bounds__(256) void k_transpose_d(const float* __restrict__ Wd,
                                                     bf16* __restrict__ WdT) {
  const float* src = Wd + (size_t)blockIdx.z * I_DIM * H_DIM;
  bf16* dst = WdT + (size_t)blockIdx.z * I_DIM * H_DIM;
  transpose_tile(src, dst, I_DIM, H_DIM);
}

// ---------------- router: fp32 logits, softmax top-2, renormalized ----------------
__global__ __launch_bounds__(256) void k_router(const float* __restrict__ x,
                                                const float* __restrict__ Wr,
                                                int* __restrict__ ridx,
                                                float* __restrict__ rw,
                                                int* __restrict__ counts) {
  int lane = threadIdx.x & 63;
  int wid  = threadIdx.x >> 6;
  int t = blockIdx.x * 4 + wid;
  const float* xr = x + (size_t)t * H_DIM;
  float acc[E_NUM];
#pragma unroll
  for (int e = 0; e < E_NUM; ++e) acc[e] = 0.f;
  for (int h = lane; h < H_DIM; h += 64) {
    float xv = xr[h];
    const float* wr = Wr + h * E_NUM;
#pragma unroll
    for (int e = 0; e < E_NUM; ++e) acc[e] += xv * wr[e];
  }
#pragma unroll
  for (int off = 32; off > 0; off >>= 1) {
#pragma unroll
    for (int e = 0; e < E_NUM; ++e) acc[e] += __shfl_xor(acc[e], off);
  }
  if (lane == 0) {
    int i0 = 0;
#pragma unroll
    for (int e = 1; e < E_NUM; ++e) if (acc[e] > acc[i0]) i0 = e;
    int i1 = (i0 == 0) ? 1 : 0;
#pragma unroll
    for (int e = 0; e < E_NUM; ++e) if (e != i0 && acc[e] > acc[i1]) i1 = e;
    float r  = expf(acc[i1] - acc[i0]);
    float w0 = 1.f / (1.f + r);
    float w1 = r / (1.f + r);
    ridx[2 * t]     = i0;
    ridx[2 * t + 1] = i1;
    rw[2 * t]     = w0;
    rw[2 * t + 1] = w1;
    atomicAdd(&counts[i0], 1);
    atomicAdd(&counts[i1], 1);
  }
}

// ------- scan: counts -> offsets, compact tile list, zero cursors -------
__global__ void k_scan(const int* __restrict__ counts, int* __restrict__ offsets,
                       int* __restrict__ cursor, int* __restrict__ tiles,
                       int* __restrict__ n_tiles) {
  if (threadIdx.x == 0) {
    int s = 0, nt = 0;
    for (int e = 0; e < E_NUM; ++e) {
      offsets[e] = s;
      int c = counts[e];
      for (int pt = 0; pt * BM < c && nt < MAXTILE; ++pt) tiles[nt++] = (e << 16) | pt;
      s += c;
    }
    offsets[E_NUM] = s;
    *n_tiles = nt;
  }
  if (threadIdx.x < E_NUM) cursor[threadIdx.x] = 0;
}

// ---------------- scatter pair ids into expert-sorted perm ----------------
__global__ __launch_bounds__(256) void k_scatter(const int* __restrict__ ridx,
                                                 const int* __restrict__ offsets,
                                                 int* __restrict__ cursor,
                                                 int* __restrict__ perm) {
  int t = blockIdx.x * 256 + threadIdx.x;
  if (t >= T_TOK) return;
#pragma unroll
  for (int k = 0; k < 2; ++k) {
    int e = ridx[2 * t + k];
    int pos = atomicAdd(&cursor[e], 1);
    perm[offsets[e] + pos] = 2 * t + k;
  }
}

// ------- fused gate+up grouped GEMM: BK=64 per barrier pair (R11 proven, 146us) -------
__global__ __launch_bounds__(256, 2) void k_gateup(const bf16* __restrict__ xb,
                                                   const bf16* __restrict__ WgT,
                                                   const bf16* __restrict__ WuT,
                                                   const int* __restrict__ perm,
                                                   const int* __restrict__ offsets,
                                                   const int* __restrict__ tiles,
                                                   const int* __restrict__ n_tiles,
                                                   bf16* __restrict__ hidden) {
  if ((int)blockIdx.y >= *n_tiles) return;
  int tv = tiles[blockIdx.y];
  int e = tv >> 16, pt = tv & 0xffff;
  int seg0 = offsets[e], cnt = offsets[e + 1] - seg0;
  int n0 = blockIdx.x * BN;

  __shared__ bf16 As[2 * HTILE];   // halves at 0, HTILE
  __shared__ bf16 Bg[2 * HTILE];
  __shared__ bf16 Bu[2 * HTILE];

  int tid = threadIdx.x, lane = tid & 63, wid = tid >> 6;
  int wm = wid >> 1, wn = wid & 1, l15 = lane & 15, l16 = lane >> 4;

  int srow1 = tid >> 2, srow2 = 64 + srow1;
  int kc = (tid & 3) * 8;
  int p1 = pt * BM + srow1, p2 = pt * BM + srow2;
  const bf16* a1 = xb + (size_t)(perm[seg0 + (p1 < cnt ? p1 : 0)] >> 1) * H_DIM + kc;
  const bf16* a2 = xb + (size_t)(perm[seg0 + (p2 < cnt ? p2 : 0)] >> 1) * H_DIM + kc;
  const bf16* g1 = WgT + ((size_t)e * I_DIM + n0 + srow1) * H_DIM + kc;
  const bf16* g2 = WgT + ((size_t)e * I_DIM + n0 + srow2) * H_DIM + kc;
  const bf16* u1 = WuT + ((size_t)e * I_DIM + n0 + srow1) * H_DIM + kc;
  const bf16* u2 = WuT + ((size_t)e * I_DIM + n0 + srow2) * H_DIM + kc;
  bf16* lA1 = &As[tid * 8];       bf16* lA2 = &As[2048 + tid * 8];
  bf16* lG1 = &Bg[tid * 8];       bf16* lG2 = &Bg[2048 + tid * 8];
  bf16* lU1 = &Bu[tid * 8];       bf16* lU2 = &Bu[2048 + tid * 8];

  f32x4 accg[4][4], accu[4][4];
#pragma unroll
  for (int m = 0; m < 4; ++m)
#pragma unroll
    for (int n = 0; n < 4; ++n) {
      accg[m][n] = (f32x4){0.f, 0.f, 0.f, 0.f};
      accu[m][n] = (f32x4){0.f, 0.f, 0.f, 0.f};
    }

  for (int k0 = 0; k0 < H_DIM; k0 += 2 * BK) {
    GL16(a1 + k0, lA1);            GL16(a2 + k0, lA2);
    GL16(a1 + k0 + BK, lA1 + HTILE); GL16(a2 + k0 + BK, lA2 + HTILE);
    GL16(g1 + k0, lG1);            GL16(g2 + k0, lG2);
    GL16(g1 + k0 + BK, lG1 + HTILE); GL16(g2 + k0 + BK, lG2 + HTILE);
    GL16(u1 + k0, lU1);            GL16(u2 + k0, lU2);
    GL16(u1 + k0 + BK, lU1 + HTILE); GL16(u2 + k0 + BK, lU2 + HTILE);
    __syncthreads();               // drains vmcnt -> both halves ready

#pragma unroll
    for (int kk = 0; kk < 2; ++kk) {
      const bf16* Ab = &As[kk * HTILE];
      const bf16* Gb = &Bg[kk * HTILE];
      const bf16* Ub = &Bu[kk * HTILE];
      bf16x8 af[4], bg[4], bu[4];
#pragma unroll
      for (int m = 0; m < 4; ++m)
        af[m] = *reinterpret_cast<const bf16x8*>(&Ab[(wm * 64 + m * 16 + l15) * BK + l16 * 8]);
#pragma unroll
      for (int n = 0; n < 4; ++n) {
        bg[n] = *reinterpret_cast<const bf16x8*>(&Gb[(wn * 64 + n * 16 + l15) * BK + l16 * 8]);
        bu[n] = *reinterpret_cast<const bf16x8*>(&Ub[(wn * 64 + n * 16 + l15) * BK + l16 * 8]);
      }
#pragma unroll
      for (int m = 0; m < 4; ++m)
#pragma unroll
        for (int n = 0; n < 4; ++n) {
          accg[m][n] = __builtin_amdgcn_mfma_f32_16x16x32_bf16(af[m], bg[n], accg[m][n], 0, 0, 0);
          accu[m][n] = __builtin_amdgcn_mfma_f32_16x16x32_bf16(af[m], bu[n], accu[m][n], 0, 0, 0);
        }
    }
    __syncthreads();
  }

#pragma unroll
  for (int m = 0; m < 4; ++m) {
#pragma unroll
    for (int r = 0; r < 4; ++r) {
      int p_glob = pt * BM + wm * 64 + m * 16 + l16 * 4 + r;
      if (p_glob < cnt) {
        bf16* hrow = hidden + (size_t)(seg0 + p_glob) * I_DIM;
#pragma unroll
        for (int n = 0; n < 4; ++n) {
          int col = n0 + wn * 64 + n * 16 + l15;
          float g = accg[m][n][r];
          float u = accu[m][n][r];
          float h = g / (1.f + __expf(-g)) * u;
          hrow[col] = (bf16)h;
        }
      }
    }
  }
}

// ------- down grouped GEMM: split-K x2 into separate bf16 partial buffers -------
__global__ __launch_bounds__(256, 2) void k_down(const bf16* __restrict__ hidden,
                                                 const bf16* __restrict__ WdT,
                                                 const int* __restrict__ perm,
                                                 const int* __restrict__ offsets,
                                                 const int* __restrict__ tiles,
                                                 const int* __restrict__ n_tiles,
                                                 bf16* __restrict__ pair_half) {
  if ((int)blockIdx.y >= *n_tiles) return;
  int tv = tiles[blockIdx.y];
  int e = tv >> 16, pt = tv & 0xffff;
  int seg0 = offsets[e], cnt = offsets[e + 1] - seg0;
  int n0 = blockIdx.x * BN;
  int kz = blockIdx.z * (I_DIM / 2);
  bf16* pout = pair_half + (size_t)blockIdx.z * 2 * T_TOK * H_DIM;

  __shared__ bf16 As[2 * HTILE];
  __shared__ bf16 Bs[2 * HTILE];

  int tid = threadIdx.x, lane = tid & 63, wid = tid >> 6;
  int wm = wid >> 1, wn = wid & 1, l15 = lane & 15, l16 = lane >> 4;

  int srow1 = tid >> 2, srow2 = 64 + srow1;
  int kc = (tid & 3) * 8;
  int p1 = pt * BM + srow1, p2 = pt * BM + srow2;
  const bf16* a1 = hidden + (size_t)(seg0 + (p1 < cnt ? p1 : 0)) * I_DIM + kz + kc;
  const bf16* a2 = hidden + (size_t)(seg0 + (p2 < cnt ? p2 : 0)) * I_DIM + kz + kc;
  const bf16* b1 = WdT + ((size_t)e * H_DIM + n0 + srow1) * I_DIM + kz + kc;
  const bf16* b2 = WdT + ((size_t)e * H_DIM + n0 + srow2) * I_DIM + kz + kc;
  bf16* lA1 = &As[tid * 8];  bf16* lA2 = &As[2048 + tid * 8];
  bf16* lB1 = &Bs[tid * 8];  bf16* lB2 = &Bs[2048 + tid * 8];

  f32x4 acc[4][4];
#pragma unroll
  for (int m = 0; m < 4; ++m)
#pragma unroll
    for (int n = 0; n < 4; ++n) acc[m][n] = (f32x4){0.f, 0.f, 0.f, 0.f};

  for (int k0 = 0; k0 < I_DIM / 2; k0 += 2 * BK) {
    GL16(a1 + k0, lA1);            GL16(a2 + k0, lA2);
    GL16(a1 + k0 + BK, lA1 + HTILE); GL16(a2 + k0 + BK, lA2 + HTILE);
    GL16(b1 + k0, lB1);            GL16(b2 + k0, lB2);
    GL16(b1 + k0 + BK, lB1 + HTILE); GL16(b2 + k0 + BK, lB2 + HTILE);
    __syncthreads();

#pragma unroll
    for (int kk = 0; kk < 2; ++kk) {
      const bf16* Ab = &As[kk * HTILE];
      const bf16* Bb = &Bs[kk * HTILE];
      bf16x8 af[4], bfr[4];
#pragma unroll
      for (int m = 0; m < 4; ++m)
        af[m] = *reinterpret_cast<const bf16x8*>(&Ab[(wm * 64 + m * 16 + l15) * BK + l16 * 8]);
#pragma unroll
      for (int n = 0; n < 4; ++n)
        bfr[n] = *reinterpret_cast<const bf16x8*>(&Bb[(wn * 64 + n * 16 + l15) * BK + l16 * 8]);
#pragma unroll
      for (int m = 0; m < 4; ++m)
#pragma unroll
        for (int n = 0; n < 4; ++n)
          acc[m][n] = __builtin_amdgcn_mfma_f32_16x16x32_bf16(af[m], bfr[n], acc[m][n], 0, 0, 0);
    }
    __syncthreads();
  }

#pragma unroll
  for (int m = 0; m < 4; ++m) {
#pragma unroll
    for (int r = 0; r < 4; ++r) {
      int p_glob = pt * BM + wm * 64 + m * 16 + l16 * 4 + r;
      if (p_glob < cnt) {
        int pair = perm[seg0 + p_glob];
        bf16* orow = pout + (size_t)pair * H_DIM;
#pragma unroll
        for (int n = 0; n < 4; ++n) {
          int col = n0 + wn * 64 + n * 16 + l15;
          orow[col] = (bf16)acc[m][n][r];
        }
      }
    }
  }
}

// ------- combine: out[t] = w0*(z0[2t]+z1[2t]) + w1*(z0[2t+1]+z1[2t+1]) -------
__global__ __launch_bounds__(256) void k_combine(const bf16* __restrict__ pair_half,
                                                 const float* __restrict__ rw,
                                                 float* __restrict__ out) {
  int t = blockIdx.x;
  int c = threadIdx.x;
  const bf16* z0 = pair_half;
  const bf16* z1 = pair_half + (size_t)2 * T_TOK * H_DIM;
  float w0 = rw[2 * t];
  float w1 = rw[2 * t + 1];
  size_t r0 = (size_t)(2 * t) * H_DIM + c * 4;
  size_t r1 = (size_t)(2 * t + 1) * H_DIM + c * 4;
  bf16x4 a0 = *reinterpret_cast<const bf16x4*>(z0 + r0);
  bf16x4 a1 = *reinterpret_cast<const bf16x4*>(z1 + r0);
  bf16x4 b0 = *reinterpret_cast<const bf16x4*>(z0 + r1);
  bf16x4 b1 = *reinterpret_cast<const bf16x4*>(z1 + r1);
  float4 o;
  o.x = w0 * ((float)a0[0] + (float)a1[0]) + w1 * ((float)b0[0] + (float)b1[0]);
  o.y = w0 * ((float)a0[1] + (float)a1[1]) + w1 * ((float)b0[1] + (float)b1[1]);
  o.z = w0 * ((float)a0[2] + (float)a1[2]) + w1 * ((float)b0[2] + (float)b1[2]);
  o.w = w0 * ((float)a0[3] + (float)a1[3]) + w1 * ((float)b0[3] + (float)b1[3]);
  *reinterpret_cast<float4*>(out + (size_t)t * H_DIM + c * 4) = o;
}

extern "C" void kernel_launch(void* const* d_in, const int* in_sizes, int n_in,
                              void* d_out, int out_size, void* d_ws, size_t ws_size,
                              hipStream_t stream) {
  const float* x  = (const float*)d_in[0];
  const float* Wr = (const float*)d_in[1];
  const float* Wg = (const float*)d_in[2];
  const float* Wu = (const float*)d_in[3];
  const float* Wd = (const float*)d_in[4];
  float* out = (float*)d_out;

  char* ws = (char*)d_ws;
  int*   counts  = (int*)(ws);
  int*   cursor  = (int*)(ws + 256);
  int*   offsets = (int*)(ws + 512);
  int*   n_tiles = (int*)(ws + 768);
  int*   tiles   = (int*)(ws + 1024);
  int*   ridx    = (int*)(ws + 64 * 1024);
  float* rw      = (float*)(ws + 128 * 1024);
  int*   perm    = (int*)(ws + 192 * 1024);
  bf16*  xb      = (bf16*)(ws + (1ull << 20));
  bf16*  WgT     = (bf16*)(ws + (16ull << 20));
  bf16*  WuT     = (bf16*)(ws + (66ull << 20));
  bf16*  WdT     = (bf16*)(ws + (116ull << 20));
  bf16*  hidden  = (bf16*)(ws + (166ull << 20));
  bf16*  pair_half = (bf16*)(ws + (212ull << 20));   // [2][8192][1024] bf16 = 32 MiB

  hipMemsetAsync(counts, 0, 64, stream);
  k_xcast<<<dim3(T_TOK * H_DIM / 2048), dim3(256), 0, stream>>>(x, xb);
  k_transpose_gu<<<dim3(I_DIM / 64, H_DIM / 64, 2 * E_NUM), dim3(256), 0, stream>>>(
      Wg, Wu, WgT, WuT);
  k_transpose_d<<<dim3(H_DIM / 64, I_DIM / 64, E_NUM), dim3(256), 0, stream>>>(Wd, WdT);
  k_router<<<dim3(T_TOK / 4), dim3(256), 0, stream>>>(x, Wr, ridx, rw, counts);
  k_scan<<<dim3(1), dim3(64), 0, stream>>>(counts, offsets, cursor, tiles, n_tiles);
  k_scatter<<<dim3((T_TOK + 255) / 256), dim3(256), 0, stream>>>(ridx, offsets, cursor, perm);
  k_gateup<<<dim3(I_DIM / BN, MAXTILE), dim3(256), 0, stream>>>(
      xb, WgT, WuT, perm, offsets, tiles, n_tiles, hidden);
  k_down<<<dim3(H_DIM / BN, MAXTILE, 2), dim3(256), 0, stream>>>(
      hidden, WdT, perm, offsets, tiles, n_tiles, pair_half);
  k_combine<<<dim3(T_TOK), dim3(256), 0, stream>>>(pair_half, rw, out);
}